// Round 3
// baseline (2726.860 us; speedup 1.0000x reference)
//
#include <hip/hip_runtime.h>
#include <hip/hip_fp16.h>
#include <math.h>

#define BSHIFT 8   // 256-node dst buckets

// ---------------- CSR build ----------------

__global__ __launch_bounds__(256) void k_deg_init(int* deg, int n) {
    int i = blockIdx.x * 256 + threadIdx.x;
    if (i < n) deg[i] = 1;  // self-loop
}

__global__ __launch_bounds__(256) void k_hist(const int* __restrict__ dst, int* deg, int E) {
    int i = blockIdx.x * 256 + threadIdx.x;
    if (i < E) atomicAdd(&deg[dst[i]], 1);
}

__global__ __launch_bounds__(256) void k_dinv(const int* __restrict__ deg, float* dinv, int n) {
    int i = blockIdx.x * 256 + threadIdx.x;
    if (i < n) {
        int d = deg[i];
        dinv[i] = d > 0 ? 1.0f / sqrtf((float)d) : 0.0f;
    }
}

#define SCAN_BS 256
__global__ __launch_bounds__(SCAN_BS) void k_scan1(const int* __restrict__ deg, int* partial,
                                                   int* blocksums, int n) {
    __shared__ int sm[SCAN_BS];
    int i = blockIdx.x * SCAN_BS + threadIdx.x;
    int v = (i < n) ? deg[i] : 0;
    sm[threadIdx.x] = v;
    __syncthreads();
    for (int off = 1; off < SCAN_BS; off <<= 1) {
        int t = 0;
        if ((int)threadIdx.x >= off) t = sm[threadIdx.x - off];
        __syncthreads();
        sm[threadIdx.x] += t;
        __syncthreads();
    }
    if (i < n) partial[i] = sm[threadIdx.x];
    if (threadIdx.x == SCAN_BS - 1) blocksums[blockIdx.x] = sm[SCAN_BS - 1];
}

__global__ __launch_bounds__(512) void k_scan2(int* blocksums, int nb) {
    __shared__ int sm[512];
    int v = ((int)threadIdx.x < nb) ? blocksums[threadIdx.x] : 0;
    sm[threadIdx.x] = v;
    __syncthreads();
    for (int off = 1; off < 512; off <<= 1) {
        int t = 0;
        if ((int)threadIdx.x >= off) t = sm[threadIdx.x - off];
        __syncthreads();
        sm[threadIdx.x] += t;
        __syncthreads();
    }
    if ((int)threadIdx.x < nb) blocksums[threadIdx.x] = threadIdx.x ? sm[threadIdx.x - 1] : 0;
}

__global__ __launch_bounds__(256) void k_scan3(const int* __restrict__ partial,
                                               const int* __restrict__ blocksums,
                                               int* rowptr, int n) {
    int i = blockIdx.x * 256 + threadIdx.x;
    if (i < n) {
        int incl = partial[i] + blocksums[i / SCAN_BS];
        rowptr[i + 1] = incl;
        if (i == 0) rowptr[0] = 0;
    }
}

// bucket cursors = CSR offset of each 256-node bucket
__global__ __launch_bounds__(256) void k_bcur(const int* __restrict__ rowptr,
                                              int* bcur, int nbkt) {
    int b = blockIdx.x * 256 + threadIdx.x;
    if (b < nbkt) bcur[b] = rowptr[b << BSHIFT];
}

// pass B: scatter packed (d&255)<<24 | s into bucket regions (dense per bucket)
__global__ __launch_bounds__(256) void k_bscat(const int* __restrict__ srcA,
                                               const int* __restrict__ dstA,
                                               int* bcur, unsigned int* bedges,
                                               int E, int n) {
    int i = blockIdx.x * 256 + threadIdx.x;
    int total = E + n;
    if (i >= total) return;
    int s, d;
    if (i < E) { s = srcA[i]; d = dstA[i]; }
    else       { s = d = i - E; }
    int pos = atomicAdd(&bcur[d >> BSHIFT], 1);
    bedges[pos] = ((unsigned int)(d & 255) << 24) | (unsigned int)s;
}

// pass C: one block per bucket; LDS per-node cursors; write col within the
// bucket's contiguous CSR region (L2-resident -> no write amplification)
__global__ __launch_bounds__(256) void k_bfill(const unsigned int* __restrict__ bedges,
                                               const int* __restrict__ rowptr,
                                               int* __restrict__ colout, int n) {
    __shared__ int lcur[256];
    int b = blockIdx.x;
    int nodeBase = b << BSHIFT;
    int cnt = n - nodeBase; if (cnt > 256) cnt = 256;
    if ((int)threadIdx.x < cnt) lcur[threadIdx.x] = rowptr[nodeBase + threadIdx.x];
    __syncthreads();
    int beg = rowptr[nodeBase];
    int end = rowptr[nodeBase + cnt];
    for (int j = beg + threadIdx.x; j < end; j += 256) {
        unsigned int e = bedges[j];
        int pos = atomicAdd(&lcur[e >> 24], 1);
        colout[pos] = (int)(e & 0x00FFFFFFu);
    }
}

// ---------------- layer kernels ----------------

__global__ __launch_bounds__(256) void k_xscale(const float* __restrict__ x,
                                                const float* __restrict__ dinv,
                                                float* __restrict__ xs, int n) {
    int i = blockIdx.x * 256 + threadIdx.x;
    if (i >= n) return;
    float dv = dinv[i];
    xs[i * 3 + 0] = dv * x[i * 3 + 0];
    xs[i * 3 + 1] = dv * x[i * 3 + 1];
    xs[i * 3 + 2] = dv * x[i * 3 + 2];
}

__global__ __launch_bounds__(256) void k_agg3(const float* __restrict__ xs,
                                              const int* __restrict__ rowptr,
                                              const int* __restrict__ col,
                                              const float* __restrict__ dinv,
                                              float* __restrict__ out3, int n) {
    int i = blockIdx.x * 256 + threadIdx.x;
    if (i >= n) return;
    float a0 = 0.f, a1 = 0.f, a2 = 0.f;
    int beg = rowptr[i], end = rowptr[i + 1];
    for (int j = beg; j < end; ++j) {
        int s = col[j];
        a0 += xs[s * 3 + 0];
        a1 += xs[s * 3 + 1];
        a2 += xs[s * 3 + 2];
    }
    float dv = dinv[i];
    out3[i * 3 + 0] = dv * a0;
    out3[i * 3 + 1] = dv * a1;
    out3[i * 3 + 2] = dv * a2;
}

__global__ __launch_bounds__(256) void k_tin(const float* __restrict__ agg3v,
                                             const float* __restrict__ Win,
                                             const float* __restrict__ bin,
                                             float* __restrict__ h, int n) {
    int idx = blockIdx.x * 256 + threadIdx.x;
    int node = idx >> 6, f = idx & 63;
    if (node >= n) return;
    float v = bin[f];
    v += agg3v[node * 3 + 0] * Win[0 * 64 + f];
    v += agg3v[node * 3 + 1] * Win[1 * 64 + f];
    v += agg3v[node * 3 + 2] * Win[2 * 64 + f];
    h[(size_t)node * 64 + f] = fmaxf(v, 0.f);
}

// dense 64x64 matmul + src dinv scale; output into 4 feature-quarter arrays:
// tq[q][node][0..15] fp16, q = f/16  (each quarter = N*32B, fits one XCD L2)
__global__ __launch_bounds__(256) void k_matmul64(const float* __restrict__ h,
                                                  const float* __restrict__ W,
                                                  const float* __restrict__ dinv,
                                                  __half* __restrict__ tq, int n) {
    __shared__ float Wl[64 * 64];
    __shared__ float Hl[16][68];
    int tid = threadIdx.x;
    for (int i = tid * 4; i < 4096; i += 1024)
        *(float4*)&Wl[i] = *(const float4*)&W[i];
    int nodeBase = blockIdx.x * 16;
    {
        int idx = tid * 4;
        int nl = idx >> 6, k = idx & 63;
        int node = nodeBase + nl;
        float4 v = make_float4(0.f, 0.f, 0.f, 0.f);
        if (node < n) v = *(const float4*)&h[(size_t)node * 64 + k];
        *(float4*)&Hl[nl][k] = v;
    }
    __syncthreads();
    int nl = tid >> 4;
    int fq = (tid & 15) * 4;
    float4 acc = make_float4(0.f, 0.f, 0.f, 0.f);
#pragma unroll
    for (int k = 0; k < 64; ++k) {
        float hv = Hl[nl][k];
        float4 wv = *(const float4*)&Wl[k * 64 + fq];
        acc.x += hv * wv.x;
        acc.y += hv * wv.y;
        acc.z += hv * wv.z;
        acc.w += hv * wv.w;
    }
    int node = nodeBase + nl;
    if (node < n) {
        float dv = dinv[node];
        int q = fq >> 4, off = fq & 15;
        __half2* dst = (__half2*)&tq[((size_t)q * n + node) * 16 + off];
        dst[0] = __floats2half2_rn(acc.x * dv, acc.y * dv);
        dst[1] = __floats2half2_rn(acc.z * dv, acc.w * dv);
    }
}

// quarter-split pull aggregation. blockIdx swizzle pins quarter q to XCDs
// {2q,2q+1} so each XCD's L2 caches one 3.25MB quarter.
// wave = one node: lanes = 8 edges x 8 half2-features; shfl_xor reduce.
__global__ __launch_bounds__(256) void k_agg16(const __half* __restrict__ tq,
                                               const int* __restrict__ rowptr,
                                               const int* __restrict__ col,
                                               const float* __restrict__ dinv,
                                               const float* __restrict__ bias,
                                               float* __restrict__ hout, int n) {
    int g = blockIdx.x;
    int xcd = g & 7;
    int q = xcd >> 1;
    int sub = xcd & 1;
    int chunk = g >> 3;
    int node = (chunk * 2 + sub) * 4 + ((int)threadIdx.x >> 6);
    if (node >= n) return;
    int lane = threadIdx.x & 63;
    int e8 = lane >> 3, f = lane & 7;
    const __half* base = tq + (size_t)q * n * 16;
    int beg = rowptr[node], end = rowptr[node + 1];
    float ax = 0.f, ay = 0.f;
    for (int j = beg + e8; j < end; j += 8) {
        int s = col[j];
        float2 vf = __half22float2(*(const __half2*)(base + (size_t)s * 16 + f * 2));
        ax += vf.x; ay += vf.y;
    }
#pragma unroll
    for (int m = 8; m < 64; m <<= 1) {
        ax += __shfl_xor(ax, m, 64);
        ay += __shfl_xor(ay, m, 64);
    }
    if (e8 == 0) {
        float dv = dinv[node];
        int fo = q * 16 + f * 2;
        float vx = dv * ax + bias[fo];
        float vy = dv * ay + bias[fo + 1];
        vx = fmaxf(vx, 0.f);
        vy = fmaxf(vy, 0.f);
        *(float2*)&hout[(size_t)node * 64 + fo] = make_float2(vx, vy);
    }
}

__global__ __launch_bounds__(256) void k_tout(const float* __restrict__ h,
                                              const float* __restrict__ Wout,
                                              const float* __restrict__ dinv,
                                              float* __restrict__ t6, int n) {
    int node = blockIdx.x * 256 + threadIdx.x;
    if (node >= n) return;
    float acc[6] = {0.f, 0.f, 0.f, 0.f, 0.f, 0.f};
#pragma unroll
    for (int k4 = 0; k4 < 16; ++k4) {
        float4 hv = *(const float4*)&h[(size_t)node * 64 + k4 * 4];
        float hq[4] = {hv.x, hv.y, hv.z, hv.w};
#pragma unroll
        for (int q = 0; q < 4; ++q) {
            int k = k4 * 4 + q;
#pragma unroll
            for (int f = 0; f < 6; ++f) acc[f] += hq[q] * Wout[k * 6 + f];
        }
    }
    float dv = dinv[node];
#pragma unroll
    for (int f = 0; f < 6; ++f) t6[node * 6 + f] = dv * acc[f];
}

__global__ __launch_bounds__(256) void k_agg6(const float* __restrict__ t6,
                                              const int* __restrict__ rowptr,
                                              const int* __restrict__ col,
                                              const float* __restrict__ dinv,
                                              const float* __restrict__ bout,
                                              float* __restrict__ out, int n) {
    int i = blockIdx.x * 256 + threadIdx.x;
    if (i >= n) return;
    float a[6] = {0.f, 0.f, 0.f, 0.f, 0.f, 0.f};
    int beg = rowptr[i], end = rowptr[i + 1];
    for (int j = beg; j < end; ++j) {
        int s = col[j];
#pragma unroll
        for (int f = 0; f < 6; ++f) a[f] += t6[s * 6 + f];
    }
    float dv = dinv[i];
#pragma unroll
    for (int f = 0; f < 6; ++f) {
        float v = dv * a[f] + bout[f];
        out[i * 6 + f] = 1.0f / (1.0f + expf(-v));
    }
}

// ---------------- host launcher ----------------

extern "C" void kernel_launch(void* const* d_in, const int* in_sizes, int n_in,
                              void* d_out, int out_size, void* d_ws, size_t ws_size,
                              hipStream_t stream) {
    const float* x    = (const float*)d_in[0];
    const int*   eidx = (const int*)d_in[1];
    const float* Win  = (const float*)d_in[2];
    const float* bin  = (const float*)d_in[3];
    const float* Whid = (const float*)d_in[4];
    const float* bhid = (const float*)d_in[5];
    const float* Wout = (const float*)d_in[6];
    const float* bout = (const float*)d_in[7];
    float* out = (float*)d_out;

    const int N = in_sizes[0] / 3;
    const int E = in_sizes[1] / 2;
    const int* srcA = eidx;
    const int* dstA = eidx + E;
    const int TOT = E + N;
    const int NBKT = (N + 255) >> BSHIFT;

    char* p = (char*)d_ws;
    auto alloc = [&](size_t bytes) -> void* {
        void* r = (void*)p;
        p += (bytes + 255) & ~(size_t)255;
        return r;
    };
    int*          deg     = (int*)alloc((size_t)N * 4);
    float*        dinv    = (float*)alloc((size_t)N * 4);
    int*          rowptr  = (int*)alloc((size_t)(N + 1) * 4);
    int*          partial = (int*)alloc((size_t)N * 4);
    int*          bsums   = (int*)alloc((size_t)512 * 4);
    int*          bcur    = (int*)alloc((size_t)NBKT * 4);
    unsigned int* bedges  = (unsigned int*)alloc((size_t)TOT * 4);
    int*          col     = (int*)alloc((size_t)TOT * 4);
    float*        xs      = (float*)alloc((size_t)N * 3 * 4);
    float*        agg3buf = (float*)alloc((size_t)N * 3 * 4);
    float*        bufA    = (float*)alloc((size_t)N * 64 * 4);   // h (fp32)
    __half*       tq      = (__half*)alloc((size_t)N * 64 * 2);  // 4 quarter arrays
    float*        t6      = (float*)alloc((size_t)N * 6 * 4);

    const int NB_N = (N + 255) / 256;
    const int NB_E = (E + 255) / 256;
    const int NB_T = (TOT + 255) / 256;

    // CSR build
    k_deg_init<<<NB_N, 256, 0, stream>>>(deg, N);
    k_hist<<<NB_E, 256, 0, stream>>>(dstA, deg, E);
    k_dinv<<<NB_N, 256, 0, stream>>>(deg, dinv, N);
    k_scan1<<<NB_N, SCAN_BS, 0, stream>>>(deg, partial, bsums, N);
    k_scan2<<<1, 512, 0, stream>>>(bsums, NB_N);
    k_scan3<<<NB_N, 256, 0, stream>>>(partial, bsums, rowptr, N);
    k_bcur<<<(NBKT + 255) / 256, 256, 0, stream>>>(rowptr, bcur, NBKT);
    k_bscat<<<NB_T, 256, 0, stream>>>(srcA, dstA, bcur, bedges, E, N);
    k_bfill<<<NBKT, 256, 0, stream>>>(bedges, rowptr, col, N);

    // input layer
    k_xscale<<<NB_N, 256, 0, stream>>>(x, dinv, xs, N);
    k_agg3<<<NB_N, 256, 0, stream>>>(xs, rowptr, col, dinv, agg3buf, N);
    k_tin<<<(N * 64 + 255) / 256, 256, 0, stream>>>(agg3buf, Win, bin, bufA, N);

    // hidden layers
    float* h = bufA;
    const int AGG_GRID = ((N + 7) / 8) * 8;  // chunk covers 8 nodes across 8 xcd slots
    for (int i = 0; i < 6; ++i) {
        k_matmul64<<<(N + 15) / 16, 256, 0, stream>>>(h, Whid + (size_t)i * 4096, dinv, tq, N);
        k_agg16<<<AGG_GRID, 256, 0, stream>>>(tq, rowptr, col, dinv, bhid + (size_t)i * 64, h, N);
    }

    // output layer
    k_tout<<<NB_N, 256, 0, stream>>>(h, Wout, dinv, t6, N);
    k_agg6<<<NB_N, 256, 0, stream>>>(t6, rowptr, col, dinv, bout, out, N);
}

// Round 5
// 1253.264 us; speedup vs baseline: 2.1758x; 2.1758x over previous
//
#include <hip/hip_runtime.h>
#include <hip/hip_fp16.h>
#include <math.h>

// ---------------- CSR build ----------------

__global__ __launch_bounds__(256) void k_deg_init(int* deg, int n) {
    int i = blockIdx.x * 256 + threadIdx.x;
    if (i < n) deg[i] = 1;  // self-loop
}

__global__ __launch_bounds__(256) void k_hist(const int* __restrict__ dst, int* deg, int E) {
    int i = blockIdx.x * 256 + threadIdx.x;
    if (i < E) atomicAdd(&deg[dst[i]], 1);
}

__global__ __launch_bounds__(256) void k_dinv(const int* __restrict__ deg, float* dinv, int n) {
    int i = blockIdx.x * 256 + threadIdx.x;
    if (i < n) {
        int d = deg[i];
        dinv[i] = d > 0 ? 1.0f / sqrtf((float)d) : 0.0f;
    }
}

#define SCAN_BS 256
__global__ __launch_bounds__(SCAN_BS) void k_scan1(const int* __restrict__ deg, int* partial,
                                                   int* blocksums, int n) {
    __shared__ int sm[SCAN_BS];
    int i = blockIdx.x * SCAN_BS + threadIdx.x;
    int v = (i < n) ? deg[i] : 0;
    sm[threadIdx.x] = v;
    __syncthreads();
    for (int off = 1; off < SCAN_BS; off <<= 1) {
        int t = 0;
        if ((int)threadIdx.x >= off) t = sm[threadIdx.x - off];
        __syncthreads();
        sm[threadIdx.x] += t;
        __syncthreads();
    }
    if (i < n) partial[i] = sm[threadIdx.x];
    if (threadIdx.x == SCAN_BS - 1) blocksums[blockIdx.x] = sm[SCAN_BS - 1];
}

__global__ __launch_bounds__(512) void k_scan2(int* blocksums, int nb) {
    __shared__ int sm[512];
    int v = ((int)threadIdx.x < nb) ? blocksums[threadIdx.x] : 0;
    sm[threadIdx.x] = v;
    __syncthreads();
    for (int off = 1; off < 512; off <<= 1) {
        int t = 0;
        if ((int)threadIdx.x >= off) t = sm[threadIdx.x - off];
        __syncthreads();
        sm[threadIdx.x] += t;
        __syncthreads();
    }
    if ((int)threadIdx.x < nb) blocksums[threadIdx.x] = threadIdx.x ? sm[threadIdx.x - 1] : 0;
}

__global__ __launch_bounds__(256) void k_scan3(const int* __restrict__ partial,
                                               const int* __restrict__ blocksums,
                                               const int* __restrict__ deg,
                                               int* rowptr, int* cursor, int n) {
    int i = blockIdx.x * 256 + threadIdx.x;
    if (i < n) {
        int incl = partial[i] + blocksums[i / SCAN_BS];
        rowptr[i + 1] = incl;
        cursor[i] = incl - deg[i];   // row start
        if (i == 0) rowptr[0] = 0;
    }
}

// range-partitioned fill: pass handles dst in [lo,hi). Per-node cursors (low
// contention); active col region ~1.9MB per pass -> writes coalesce in L2.
__global__ __launch_bounds__(256) void k_fillp(const int* __restrict__ srcA,
                                               const int* __restrict__ dstA,
                                               int* cursor, int* col,
                                               int E, int n, int lo, int hi) {
    int i = blockIdx.x * 256 + threadIdx.x;
    int total = E + n;
    if (i >= total) return;
    int s, d;
    if (i < E) { s = srcA[i]; d = dstA[i]; }
    else       { s = d = i - E; }
    if (d < lo || d >= hi) return;
    int pos = atomicAdd(&cursor[d], 1);
    col[pos] = s;
}

// ---------------- layer kernels ----------------

__global__ __launch_bounds__(256) void k_xscale(const float* __restrict__ x,
                                                const float* __restrict__ dinv,
                                                float* __restrict__ xs, int n) {
    int i = blockIdx.x * 256 + threadIdx.x;
    if (i >= n) return;
    float dv = dinv[i];
    xs[i * 3 + 0] = dv * x[i * 3 + 0];
    xs[i * 3 + 1] = dv * x[i * 3 + 1];
    xs[i * 3 + 2] = dv * x[i * 3 + 2];
}

__global__ __launch_bounds__(256) void k_agg3(const float* __restrict__ xs,
                                              const int* __restrict__ rowptr,
                                              const int* __restrict__ col,
                                              const float* __restrict__ dinv,
                                              float* __restrict__ out3, int n) {
    int i = blockIdx.x * 256 + threadIdx.x;
    if (i >= n) return;
    float a0 = 0.f, a1 = 0.f, a2 = 0.f;
    int beg = rowptr[i], end = rowptr[i + 1];
    for (int j = beg; j < end; ++j) {
        int s = col[j];
        a0 += xs[s * 3 + 0];
        a1 += xs[s * 3 + 1];
        a2 += xs[s * 3 + 2];
    }
    float dv = dinv[i];
    out3[i * 3 + 0] = dv * a0;
    out3[i * 3 + 1] = dv * a1;
    out3[i * 3 + 2] = dv * a2;
}

__global__ __launch_bounds__(256) void k_tin(const float* __restrict__ agg3v,
                                             const float* __restrict__ Win,
                                             const float* __restrict__ bin,
                                             float* __restrict__ h, int n) {
    int idx = blockIdx.x * 256 + threadIdx.x;
    int node = idx >> 6, f = idx & 63;
    if (node >= n) return;
    float v = bin[f];
    v += agg3v[node * 3 + 0] * Win[0 * 64 + f];
    v += agg3v[node * 3 + 1] * Win[1 * 64 + f];
    v += agg3v[node * 3 + 2] * Win[2 * 64 + f];
    h[(size_t)node * 64 + f] = fmaxf(v, 0.f);
}

// dense 64x64 matmul + src-side dinv scale, fp16 output row [node][64]
__global__ __launch_bounds__(256) void k_matmul64(const float* __restrict__ h,
                                                  const float* __restrict__ W,
                                                  const float* __restrict__ dinv,
                                                  __half* __restrict__ t16, int n) {
    __shared__ float Wl[64 * 64];
    __shared__ float Hl[16][68];
    int tid = threadIdx.x;
    for (int i = tid * 4; i < 4096; i += 1024)
        *(float4*)&Wl[i] = *(const float4*)&W[i];
    int nodeBase = blockIdx.x * 16;
    {
        int idx = tid * 4;
        int nl = idx >> 6, k = idx & 63;
        int node = nodeBase + nl;
        float4 v = make_float4(0.f, 0.f, 0.f, 0.f);
        if (node < n) v = *(const float4*)&h[(size_t)node * 64 + k];
        *(float4*)&Hl[nl][k] = v;
    }
    __syncthreads();
    int nl = tid >> 4;
    int fq = (tid & 15) * 4;
    float4 acc = make_float4(0.f, 0.f, 0.f, 0.f);
#pragma unroll
    for (int k = 0; k < 64; ++k) {
        float hv = Hl[nl][k];
        float4 wv = *(const float4*)&Wl[k * 64 + fq];
        acc.x += hv * wv.x;
        acc.y += hv * wv.y;
        acc.z += hv * wv.z;
        acc.w += hv * wv.w;
    }
    int node = nodeBase + nl;
    if (node < n) {
        float dv = dinv[node];
        __half2* dst = (__half2*)&t16[(size_t)node * 64 + fq];
        dst[0] = __floats2half2_rn(acc.x * dv, acc.y * dv);
        dst[1] = __floats2half2_rn(acc.z * dv, acc.w * dv);
    }
}

// pull aggregation: 2 nodes per wave, 32 lanes per node, lane = feature pair.
// half2 loads (4B/lane), 2-edge unroll for MLP.
__global__ __launch_bounds__(256) void k_agg64(const __half* __restrict__ t16,
                                               const int* __restrict__ rowptr,
                                               const int* __restrict__ col,
                                               const float* __restrict__ dinv,
                                               const float* __restrict__ bias,
                                               float* __restrict__ hout, int n) {
    int node = blockIdx.x * 8 + ((int)threadIdx.x >> 5);
    int f2 = threadIdx.x & 31;
    if (node >= n) return;
    int beg = rowptr[node], end = rowptr[node + 1];
    float ax = 0.f, ay = 0.f;
    int j = beg;
    for (; j + 1 < end; j += 2) {
        int s0 = col[j], s1 = col[j + 1];
        float2 v0 = __half22float2(*(const __half2*)(t16 + (size_t)s0 * 64 + f2 * 2));
        float2 v1 = __half22float2(*(const __half2*)(t16 + (size_t)s1 * 64 + f2 * 2));
        ax += v0.x + v1.x;
        ay += v0.y + v1.y;
    }
    if (j < end) {
        int s0 = col[j];
        float2 v0 = __half22float2(*(const __half2*)(t16 + (size_t)s0 * 64 + f2 * 2));
        ax += v0.x;
        ay += v0.y;
    }
    float dv = dinv[node];
    float vx = fmaxf(dv * ax + bias[f2 * 2 + 0], 0.f);
    float vy = fmaxf(dv * ay + bias[f2 * 2 + 1], 0.f);
    *(float2*)&hout[(size_t)node * 64 + f2 * 2] = make_float2(vx, vy);
}

__global__ __launch_bounds__(256) void k_tout(const float* __restrict__ h,
                                              const float* __restrict__ Wout,
                                              const float* __restrict__ dinv,
                                              float* __restrict__ t6, int n) {
    int node = blockIdx.x * 256 + threadIdx.x;
    if (node >= n) return;
    float acc[6] = {0.f, 0.f, 0.f, 0.f, 0.f, 0.f};
#pragma unroll
    for (int k4 = 0; k4 < 16; ++k4) {
        float4 hv = *(const float4*)&h[(size_t)node * 64 + k4 * 4];
        float hq[4] = {hv.x, hv.y, hv.z, hv.w};
#pragma unroll
        for (int q = 0; q < 4; ++q) {
            int k = k4 * 4 + q;
#pragma unroll
            for (int f = 0; f < 6; ++f) acc[f] += hq[q] * Wout[k * 6 + f];
        }
    }
    float dv = dinv[node];
#pragma unroll
    for (int f = 0; f < 6; ++f) t6[node * 6 + f] = dv * acc[f];
}

__global__ __launch_bounds__(256) void k_agg6(const float* __restrict__ t6,
                                              const int* __restrict__ rowptr,
                                              const int* __restrict__ col,
                                              const float* __restrict__ dinv,
                                              const float* __restrict__ bout,
                                              float* __restrict__ out, int n) {
    int i = blockIdx.x * 256 + threadIdx.x;
    if (i >= n) return;
    float a[6] = {0.f, 0.f, 0.f, 0.f, 0.f, 0.f};
    int beg = rowptr[i], end = rowptr[i + 1];
    for (int j = beg; j < end; ++j) {
        int s = col[j];
#pragma unroll
        for (int f = 0; f < 6; ++f) a[f] += t6[s * 6 + f];
    }
    float dv = dinv[i];
#pragma unroll
    for (int f = 0; f < 6; ++f) {
        float v = dv * a[f] + bout[f];
        out[i * 6 + f] = 1.0f / (1.0f + expf(-v));
    }
}

// ---------------- host launcher ----------------

extern "C" void kernel_launch(void* const* d_in, const int* in_sizes, int n_in,
                              void* d_out, int out_size, void* d_ws, size_t ws_size,
                              hipStream_t stream) {
    const float* x    = (const float*)d_in[0];
    const int*   eidx = (const int*)d_in[1];
    const float* Win  = (const float*)d_in[2];
    const float* bin  = (const float*)d_in[3];
    const float* Whid = (const float*)d_in[4];
    const float* bhid = (const float*)d_in[5];
    const float* Wout = (const float*)d_in[6];
    const float* bout = (const float*)d_in[7];
    float* out = (float*)d_out;

    const int N = in_sizes[0] / 3;
    const int E = in_sizes[1] / 2;
    const int* srcA = eidx;
    const int* dstA = eidx + E;
    const int TOT = E + N;

    char* p = (char*)d_ws;
    auto alloc = [&](size_t bytes) -> void* {
        void* r = (void*)p;
        p += (bytes + 255) & ~(size_t)255;
        return r;
    };
    int*    deg     = (int*)alloc((size_t)N * 4);
    float*  dinv    = (float*)alloc((size_t)N * 4);
    int*    rowptr  = (int*)alloc((size_t)(N + 1) * 4);
    int*    cursor  = (int*)alloc((size_t)N * 4);
    int*    partial = (int*)alloc((size_t)N * 4);
    int*    bsums   = (int*)alloc((size_t)512 * 4);
    int*    col     = (int*)alloc((size_t)TOT * 4);
    float*  xs      = (float*)alloc((size_t)N * 3 * 4);
    float*  agg3buf = (float*)alloc((size_t)N * 3 * 4);
    float*  bufA    = (float*)alloc((size_t)N * 64 * 4);   // h (fp32)
    __half* t16     = (__half*)alloc((size_t)N * 64 * 2);  // scaled transform (fp16)
    float*  t6      = (float*)alloc((size_t)N * 6 * 4);

    const int NB_N = (N + 255) / 256;
    const int NB_E = (E + 255) / 256;
    const int NB_T = (TOT + 255) / 256;

    // CSR build
    k_deg_init<<<NB_N, 256, 0, stream>>>(deg, N);
    k_hist<<<NB_E, 256, 0, stream>>>(dstA, deg, E);
    k_dinv<<<NB_N, 256, 0, stream>>>(deg, dinv, N);
    k_scan1<<<NB_N, SCAN_BS, 0, stream>>>(deg, partial, bsums, N);
    k_scan2<<<1, 512, 0, stream>>>(bsums, NB_N);
    k_scan3<<<NB_N, 256, 0, stream>>>(partial, bsums, deg, rowptr, cursor, N);

    // multi-pass range-partitioned fill (L2-resident col region per pass)
    const int RSIZE = 16384;
    for (int lo = 0; lo < N; lo += RSIZE) {
        int hi = lo + RSIZE; if (hi > N) hi = N;
        k_fillp<<<NB_T, 256, 0, stream>>>(srcA, dstA, cursor, col, E, N, lo, hi);
    }

    // input layer
    k_xscale<<<NB_N, 256, 0, stream>>>(x, dinv, xs, N);
    k_agg3<<<NB_N, 256, 0, stream>>>(xs, rowptr, col, dinv, agg3buf, N);
    k_tin<<<(N * 64 + 255) / 256, 256, 0, stream>>>(agg3buf, Win, bin, bufA, N);

    // hidden layers
    float* h = bufA;
    for (int i = 0; i < 6; ++i) {
        k_matmul64<<<(N + 15) / 16, 256, 0, stream>>>(h, Whid + (size_t)i * 4096, dinv, t16, N);
        k_agg64<<<(N + 7) / 8, 256, 0, stream>>>(t16, rowptr, col, dinv, bhid + (size_t)i * 64, h, N);
    }

    // output layer
    k_tout<<<NB_N, 256, 0, stream>>>(h, Wout, dinv, t6, N);
    k_agg6<<<NB_N, 256, 0, stream>>>(t6, rowptr, col, dinv, bout, out, N);
}

// Round 6
// 1065.557 us; speedup vs baseline: 2.5591x; 1.1762x over previous
//
#include <hip/hip_runtime.h>
#include <hip/hip_fp16.h>
#include <math.h>

// ---------------- CSR build ----------------

__global__ __launch_bounds__(256) void k_deg_init(int* deg, int n) {
    int i = blockIdx.x * 256 + threadIdx.x;
    if (i < n) deg[i] = 1;  // self-loop
}

// range-partitioned histogram: only dst in [lo,hi) -> active 64KB deg window
// stays L2-resident despite the streaming edge-list read (R5 lesson: full-range
// hist thrashed deg lines to HBM, 128us & 100MB writes).
__global__ __launch_bounds__(256) void k_histp(const int* __restrict__ dst, int* deg,
                                               int E, int lo, int hi) {
    int i = blockIdx.x * 256 + threadIdx.x;
    if (i >= E) return;
    int d = dst[i];
    if (d >= lo && d < hi) atomicAdd(&deg[d], 1);
}

__global__ __launch_bounds__(256) void k_dinv(const int* __restrict__ deg, float* dinv, int n) {
    int i = blockIdx.x * 256 + threadIdx.x;
    if (i < n) {
        int d = deg[i];
        dinv[i] = d > 0 ? 1.0f / sqrtf((float)d) : 0.0f;
    }
}

#define SCAN_BS 256
__global__ __launch_bounds__(SCAN_BS) void k_scan1(const int* __restrict__ deg, int* partial,
                                                   int* blocksums, int n) {
    __shared__ int sm[SCAN_BS];
    int i = blockIdx.x * SCAN_BS + threadIdx.x;
    int v = (i < n) ? deg[i] : 0;
    sm[threadIdx.x] = v;
    __syncthreads();
    for (int off = 1; off < SCAN_BS; off <<= 1) {
        int t = 0;
        if ((int)threadIdx.x >= off) t = sm[threadIdx.x - off];
        __syncthreads();
        sm[threadIdx.x] += t;
        __syncthreads();
    }
    if (i < n) partial[i] = sm[threadIdx.x];
    if (threadIdx.x == SCAN_BS - 1) blocksums[blockIdx.x] = sm[SCAN_BS - 1];
}

__global__ __launch_bounds__(512) void k_scan2(int* blocksums, int nb) {
    __shared__ int sm[512];
    int v = ((int)threadIdx.x < nb) ? blocksums[threadIdx.x] : 0;
    sm[threadIdx.x] = v;
    __syncthreads();
    for (int off = 1; off < 512; off <<= 1) {
        int t = 0;
        if ((int)threadIdx.x >= off) t = sm[threadIdx.x - off];
        __syncthreads();
        sm[threadIdx.x] += t;
        __syncthreads();
    }
    if ((int)threadIdx.x < nb) blocksums[threadIdx.x] = threadIdx.x ? sm[threadIdx.x - 1] : 0;
}

__global__ __launch_bounds__(256) void k_scan3(const int* __restrict__ partial,
                                               const int* __restrict__ blocksums,
                                               const int* __restrict__ deg,
                                               int* rowptr, int* cursor, int n) {
    int i = blockIdx.x * 256 + threadIdx.x;
    if (i < n) {
        int incl = partial[i] + blocksums[i / SCAN_BS];
        rowptr[i + 1] = incl;
        cursor[i] = incl - deg[i];   // row start
        if (i == 0) rowptr[0] = 0;
    }
}

// range-partitioned fill (R5-proven): active col region L2-resident per pass.
__global__ __launch_bounds__(256) void k_fillp(const int* __restrict__ srcA,
                                               const int* __restrict__ dstA,
                                               int* cursor, int* col,
                                               int E, int n, int lo, int hi) {
    int i = blockIdx.x * 256 + threadIdx.x;
    int total = E + n;
    if (i >= total) return;
    int s, d;
    if (i < E) { s = srcA[i]; d = dstA[i]; }
    else       { s = d = i - E; }
    if (d < lo || d >= hi) return;
    int pos = atomicAdd(&cursor[d], 1);
    col[pos] = s;
}

// ---------------- layer kernels ----------------

__global__ __launch_bounds__(256) void k_xscale(const float* __restrict__ x,
                                                const float* __restrict__ dinv,
                                                float* __restrict__ xs, int n) {
    int i = blockIdx.x * 256 + threadIdx.x;
    if (i >= n) return;
    float dv = dinv[i];
    xs[i * 3 + 0] = dv * x[i * 3 + 0];
    xs[i * 3 + 1] = dv * x[i * 3 + 1];
    xs[i * 3 + 2] = dv * x[i * 3 + 2];
}

__global__ __launch_bounds__(256) void k_agg3(const float* __restrict__ xs,
                                              const int* __restrict__ rowptr,
                                              const int* __restrict__ col,
                                              const float* __restrict__ dinv,
                                              float* __restrict__ out3, int n) {
    int i = blockIdx.x * 256 + threadIdx.x;
    if (i >= n) return;
    float a0 = 0.f, a1 = 0.f, a2 = 0.f;
    int beg = rowptr[i], end = rowptr[i + 1];
    for (int j = beg; j < end; ++j) {
        int s = col[j];
        a0 += xs[s * 3 + 0];
        a1 += xs[s * 3 + 1];
        a2 += xs[s * 3 + 2];
    }
    float dv = dinv[i];
    out3[i * 3 + 0] = dv * a0;
    out3[i * 3 + 1] = dv * a1;
    out3[i * 3 + 2] = dv * a2;
}

__global__ __launch_bounds__(256) void k_tin(const float* __restrict__ agg3v,
                                             const float* __restrict__ Win,
                                             const float* __restrict__ bin,
                                             float* __restrict__ h, int n) {
    int idx = blockIdx.x * 256 + threadIdx.x;
    int node = idx >> 6, f = idx & 63;
    if (node >= n) return;
    float v = bin[f];
    v += agg3v[node * 3 + 0] * Win[0 * 64 + f];
    v += agg3v[node * 3 + 1] * Win[1 * 64 + f];
    v += agg3v[node * 3 + 2] * Win[2 * 64 + f];
    h[(size_t)node * 64 + f] = fmaxf(v, 0.f);
}

// dense 64x64 matmul + src-side dinv scale, fp16 output row [node][64]
__global__ __launch_bounds__(256) void k_matmul64(const float* __restrict__ h,
                                                  const float* __restrict__ W,
                                                  const float* __restrict__ dinv,
                                                  __half* __restrict__ t16, int n) {
    __shared__ float Wl[64 * 64];
    __shared__ float Hl[16][68];
    int tid = threadIdx.x;
    for (int i = tid * 4; i < 4096; i += 1024)
        *(float4*)&Wl[i] = *(const float4*)&W[i];
    int nodeBase = blockIdx.x * 16;
    {
        int idx = tid * 4;
        int nl = idx >> 6, k = idx & 63;
        int node = nodeBase + nl;
        float4 v = make_float4(0.f, 0.f, 0.f, 0.f);
        if (node < n) v = *(const float4*)&h[(size_t)node * 64 + k];
        *(float4*)&Hl[nl][k] = v;
    }
    __syncthreads();
    int nl = tid >> 4;
    int fq = (tid & 15) * 4;
    float4 acc = make_float4(0.f, 0.f, 0.f, 0.f);
#pragma unroll
    for (int k = 0; k < 64; ++k) {
        float hv = Hl[nl][k];
        float4 wv = *(const float4*)&Wl[k * 64 + fq];
        acc.x += hv * wv.x;
        acc.y += hv * wv.y;
        acc.z += hv * wv.z;
        acc.w += hv * wv.w;
    }
    int node = nodeBase + nl;
    if (node < n) {
        float dv = dinv[node];
        __half2* dst = (__half2*)&t16[(size_t)node * 64 + fq];
        dst[0] = __floats2half2_rn(acc.x * dv, acc.y * dv);
        dst[1] = __floats2half2_rn(acc.z * dv, acc.w * dv);
    }
}

// pull aggregation v2: 1 node per wave; 64 lanes = 8 edge-slots x 8 feat-lanes.
// Each lane loads 16B (8 fp16 feats) -> 4x fewer VMEM instrs than half2 lanes;
// 8 edges in flight per wave; slot-reduce via 3 shfl_xor steps.
__global__ __launch_bounds__(256) void k_agg64(const __half* __restrict__ t16,
                                               const int* __restrict__ rowptr,
                                               const int* __restrict__ col,
                                               const float* __restrict__ dinv,
                                               const float* __restrict__ bias,
                                               float* __restrict__ hout, int n) {
    int node = blockIdx.x * 4 + ((int)threadIdx.x >> 6);
    if (node >= n) return;
    int lane = threadIdx.x & 63;
    int slot = lane >> 3;   // 0..7 edge slot
    int fl   = lane & 7;    // feature lane: feats [fl*8, fl*8+8)
    int beg = rowptr[node], end = rowptr[node + 1];
    float a0 = 0.f, a1 = 0.f, a2 = 0.f, a3 = 0.f, a4 = 0.f, a5 = 0.f, a6 = 0.f, a7 = 0.f;
    for (int j = beg + slot; j < end; j += 8) {
        int s = col[j];
        float4 raw = *(const float4*)(t16 + (size_t)s * 64 + fl * 8);
        const __half2* hp = (const __half2*)&raw;
        float2 p0 = __half22float2(hp[0]);
        float2 p1 = __half22float2(hp[1]);
        float2 p2 = __half22float2(hp[2]);
        float2 p3 = __half22float2(hp[3]);
        a0 += p0.x; a1 += p0.y; a2 += p1.x; a3 += p1.y;
        a4 += p2.x; a5 += p2.y; a6 += p3.x; a7 += p3.y;
    }
#pragma unroll
    for (int m = 8; m < 64; m <<= 1) {
        a0 += __shfl_xor(a0, m, 64);
        a1 += __shfl_xor(a1, m, 64);
        a2 += __shfl_xor(a2, m, 64);
        a3 += __shfl_xor(a3, m, 64);
        a4 += __shfl_xor(a4, m, 64);
        a5 += __shfl_xor(a5, m, 64);
        a6 += __shfl_xor(a6, m, 64);
        a7 += __shfl_xor(a7, m, 64);
    }
    if (slot == 0) {
        float dv = dinv[node];
        int fo = fl * 8;
        float4 w0, w1;
        w0.x = fmaxf(dv * a0 + bias[fo + 0], 0.f);
        w0.y = fmaxf(dv * a1 + bias[fo + 1], 0.f);
        w0.z = fmaxf(dv * a2 + bias[fo + 2], 0.f);
        w0.w = fmaxf(dv * a3 + bias[fo + 3], 0.f);
        w1.x = fmaxf(dv * a4 + bias[fo + 4], 0.f);
        w1.y = fmaxf(dv * a5 + bias[fo + 5], 0.f);
        w1.z = fmaxf(dv * a6 + bias[fo + 6], 0.f);
        w1.w = fmaxf(dv * a7 + bias[fo + 7], 0.f);
        *(float4*)&hout[(size_t)node * 64 + fo] = w0;
        *(float4*)&hout[(size_t)node * 64 + fo + 4] = w1;
    }
}

__global__ __launch_bounds__(256) void k_tout(const float* __restrict__ h,
                                              const float* __restrict__ Wout,
                                              const float* __restrict__ dinv,
                                              float* __restrict__ t6, int n) {
    int node = blockIdx.x * 256 + threadIdx.x;
    if (node >= n) return;
    float acc[6] = {0.f, 0.f, 0.f, 0.f, 0.f, 0.f};
#pragma unroll
    for (int k4 = 0; k4 < 16; ++k4) {
        float4 hv = *(const float4*)&h[(size_t)node * 64 + k4 * 4];
        float hq[4] = {hv.x, hv.y, hv.z, hv.w};
#pragma unroll
        for (int q = 0; q < 4; ++q) {
            int k = k4 * 4 + q;
#pragma unroll
            for (int f = 0; f < 6; ++f) acc[f] += hq[q] * Wout[k * 6 + f];
        }
    }
    float dv = dinv[node];
#pragma unroll
    for (int f = 0; f < 6; ++f) t6[node * 6 + f] = dv * acc[f];
}

__global__ __launch_bounds__(256) void k_agg6(const float* __restrict__ t6,
                                              const int* __restrict__ rowptr,
                                              const int* __restrict__ col,
                                              const float* __restrict__ dinv,
                                              const float* __restrict__ bout,
                                              float* __restrict__ out, int n) {
    int i = blockIdx.x * 256 + threadIdx.x;
    if (i >= n) return;
    float a[6] = {0.f, 0.f, 0.f, 0.f, 0.f, 0.f};
    int beg = rowptr[i], end = rowptr[i + 1];
    for (int j = beg; j < end; ++j) {
        int s = col[j];
#pragma unroll
        for (int f = 0; f < 6; ++f) a[f] += t6[s * 6 + f];
    }
    float dv = dinv[i];
#pragma unroll
    for (int f = 0; f < 6; ++f) {
        float v = dv * a[f] + bout[f];
        out[i * 6 + f] = 1.0f / (1.0f + expf(-v));
    }
}

// ---------------- host launcher ----------------

extern "C" void kernel_launch(void* const* d_in, const int* in_sizes, int n_in,
                              void* d_out, int out_size, void* d_ws, size_t ws_size,
                              hipStream_t stream) {
    const float* x    = (const float*)d_in[0];
    const int*   eidx = (const int*)d_in[1];
    const float* Win  = (const float*)d_in[2];
    const float* bin  = (const float*)d_in[3];
    const float* Whid = (const float*)d_in[4];
    const float* bhid = (const float*)d_in[5];
    const float* Wout = (const float*)d_in[6];
    const float* bout = (const float*)d_in[7];
    float* out = (float*)d_out;

    const int N = in_sizes[0] / 3;
    const int E = in_sizes[1] / 2;
    const int* srcA = eidx;
    const int* dstA = eidx + E;
    const int TOT = E + N;

    char* p = (char*)d_ws;
    auto alloc = [&](size_t bytes) -> void* {
        void* r = (void*)p;
        p += (bytes + 255) & ~(size_t)255;
        return r;
    };
    int*    deg     = (int*)alloc((size_t)N * 4);
    float*  dinv    = (float*)alloc((size_t)N * 4);
    int*    rowptr  = (int*)alloc((size_t)(N + 1) * 4);
    int*    cursor  = (int*)alloc((size_t)N * 4);
    int*    partial = (int*)alloc((size_t)N * 4);
    int*    bsums   = (int*)alloc((size_t)512 * 4);
    int*    col     = (int*)alloc((size_t)TOT * 4);
    float*  xs      = (float*)alloc((size_t)N * 3 * 4);
    float*  agg3buf = (float*)alloc((size_t)N * 3 * 4);
    float*  bufA    = (float*)alloc((size_t)N * 64 * 4);   // h (fp32)
    __half* t16     = (__half*)alloc((size_t)N * 64 * 2);  // scaled transform (fp16)
    float*  t6      = (float*)alloc((size_t)N * 6 * 4);

    const int NB_N = (N + 255) / 256;
    const int NB_E = (E + 255) / 256;
    const int NB_T = (TOT + 255) / 256;

    // CSR build
    k_deg_init<<<NB_N, 256, 0, stream>>>(deg, N);
    const int RSIZE = 16384;
    for (int lo = 0; lo < N; lo += RSIZE) {
        int hi = lo + RSIZE; if (hi > N) hi = N;
        k_histp<<<NB_E, 256, 0, stream>>>(dstA, deg, E, lo, hi);
    }
    k_dinv<<<NB_N, 256, 0, stream>>>(deg, dinv, N);
    k_scan1<<<NB_N, SCAN_BS, 0, stream>>>(deg, partial, bsums, N);
    k_scan2<<<1, 512, 0, stream>>>(bsums, NB_N);
    k_scan3<<<NB_N, 256, 0, stream>>>(partial, bsums, deg, rowptr, cursor, N);

    // multi-pass range-partitioned fill (L2-resident col region per pass)
    for (int lo = 0; lo < N; lo += RSIZE) {
        int hi = lo + RSIZE; if (hi > N) hi = N;
        k_fillp<<<NB_T, 256, 0, stream>>>(srcA, dstA, cursor, col, E, N, lo, hi);
    }

    // input layer
    k_xscale<<<NB_N, 256, 0, stream>>>(x, dinv, xs, N);
    k_agg3<<<NB_N, 256, 0, stream>>>(xs, rowptr, col, dinv, agg3buf, N);
    k_tin<<<(N * 64 + 255) / 256, 256, 0, stream>>>(agg3buf, Win, bin, bufA, N);

    // hidden layers
    float* h = bufA;
    for (int i = 0; i < 6; ++i) {
        k_matmul64<<<(N + 15) / 16, 256, 0, stream>>>(h, Whid + (size_t)i * 4096, dinv, t16, N);
        k_agg64<<<(N + 3) / 4, 256, 0, stream>>>(t16, rowptr, col, dinv, bhid + (size_t)i * 64, h, N);
    }

    // output layer
    k_tout<<<NB_N, 256, 0, stream>>>(h, Wout, dinv, t6, N);
    k_agg6<<<NB_N, 256, 0, stream>>>(t6, rowptr, col, dinv, bout, out, N);
}

// Round 7
// 928.750 us; speedup vs baseline: 2.9361x; 1.1473x over previous
//
#include <hip/hip_runtime.h>
#include <hip/hip_fp16.h>
#include <math.h>

#define RSIZE 16384   // dst-range partition size for CSR build (R5-proven)

// ---------------- CSR build ----------------

__global__ __launch_bounds__(256) void k_deg_init(int* deg, int n) {
    int i = blockIdx.x * 256 + threadIdx.x;
    if (i < n) deg[i] = 1;  // self-loop
}

// merged range-partitioned histogram: blockIdx = range * nbE + chunk.
// Blocks of one range dispatch together -> active 64KB deg window stays hot.
__global__ __launch_bounds__(256) void k_histp_all(const int* __restrict__ dst, int* deg,
                                                   int E, int n, int nbE) {
    int r = blockIdx.x / nbE;
    int chunk = blockIdx.x % nbE;
    int i = chunk * 256 + threadIdx.x;
    if (i >= E) return;
    int lo = r * RSIZE;
    int hi = lo + RSIZE; if (hi > n) hi = n;
    int d = dst[i];
    if (d >= lo && d < hi) atomicAdd(&deg[d], 1);
}

__global__ __launch_bounds__(256) void k_dinv(const int* __restrict__ deg, float* dinv, int n) {
    int i = blockIdx.x * 256 + threadIdx.x;
    if (i < n) {
        int d = deg[i];
        dinv[i] = d > 0 ? 1.0f / sqrtf((float)d) : 0.0f;
    }
}

#define SCAN_BS 256
__global__ __launch_bounds__(SCAN_BS) void k_scan1(const int* __restrict__ deg, int* partial,
                                                   int* blocksums, int n) {
    __shared__ int sm[SCAN_BS];
    int i = blockIdx.x * SCAN_BS + threadIdx.x;
    int v = (i < n) ? deg[i] : 0;
    sm[threadIdx.x] = v;
    __syncthreads();
    for (int off = 1; off < SCAN_BS; off <<= 1) {
        int t = 0;
        if ((int)threadIdx.x >= off) t = sm[threadIdx.x - off];
        __syncthreads();
        sm[threadIdx.x] += t;
        __syncthreads();
    }
    if (i < n) partial[i] = sm[threadIdx.x];
    if (threadIdx.x == SCAN_BS - 1) blocksums[blockIdx.x] = sm[SCAN_BS - 1];
}

__global__ __launch_bounds__(512) void k_scan2(int* blocksums, int nb) {
    __shared__ int sm[512];
    int v = ((int)threadIdx.x < nb) ? blocksums[threadIdx.x] : 0;
    sm[threadIdx.x] = v;
    __syncthreads();
    for (int off = 1; off < 512; off <<= 1) {
        int t = 0;
        if ((int)threadIdx.x >= off) t = sm[threadIdx.x - off];
        __syncthreads();
        sm[threadIdx.x] += t;
        __syncthreads();
    }
    if ((int)threadIdx.x < nb) blocksums[threadIdx.x] = threadIdx.x ? sm[threadIdx.x - 1] : 0;
}

__global__ __launch_bounds__(256) void k_scan3(const int* __restrict__ partial,
                                               const int* __restrict__ blocksums,
                                               const int* __restrict__ deg,
                                               int* rowptr, int* cursor, int n) {
    int i = blockIdx.x * 256 + threadIdx.x;
    if (i < n) {
        int incl = partial[i] + blocksums[i / SCAN_BS];
        rowptr[i + 1] = incl;
        cursor[i] = incl - deg[i];   // row start
        if (i == 0) rowptr[0] = 0;
    }
}

// merged range-partitioned fill: active col region L2-resident per range.
__global__ __launch_bounds__(256) void k_fillp_all(const int* __restrict__ srcA,
                                                   const int* __restrict__ dstA,
                                                   int* cursor, int* col,
                                                   int E, int n, int nbT) {
    int r = blockIdx.x / nbT;
    int chunk = blockIdx.x % nbT;
    int i = chunk * 256 + threadIdx.x;
    int total = E + n;
    if (i >= total) return;
    int lo = r * RSIZE;
    int hi = lo + RSIZE; if (hi > n) hi = n;
    int s, d;
    if (i < E) { s = srcA[i]; d = dstA[i]; }
    else       { s = d = i - E; }
    if (d < lo || d >= hi) return;
    int pos = atomicAdd(&cursor[d], 1);
    col[pos] = s;
}

// ---------------- layer kernels ----------------

__global__ __launch_bounds__(256) void k_xscale(const float* __restrict__ x,
                                                const float* __restrict__ dinv,
                                                float* __restrict__ xs, int n) {
    int i = blockIdx.x * 256 + threadIdx.x;
    if (i >= n) return;
    float dv = dinv[i];
    xs[i * 3 + 0] = dv * x[i * 3 + 0];
    xs[i * 3 + 1] = dv * x[i * 3 + 1];
    xs[i * 3 + 2] = dv * x[i * 3 + 2];
}

__global__ __launch_bounds__(256) void k_agg3(const float* __restrict__ xs,
                                              const int* __restrict__ rowptr,
                                              const int* __restrict__ col,
                                              const float* __restrict__ dinv,
                                              float* __restrict__ out3, int n) {
    int i = blockIdx.x * 256 + threadIdx.x;
    if (i >= n) return;
    float a0 = 0.f, a1 = 0.f, a2 = 0.f;
    int beg = rowptr[i], end = rowptr[i + 1];
    for (int j = beg; j < end; ++j) {
        int s = col[j];
        a0 += xs[s * 3 + 0];
        a1 += xs[s * 3 + 1];
        a2 += xs[s * 3 + 2];
    }
    float dv = dinv[i];
    out3[i * 3 + 0] = dv * a0;
    out3[i * 3 + 1] = dv * a1;
    out3[i * 3 + 2] = dv * a2;
}

// input transform -> h fp16
__global__ __launch_bounds__(256) void k_tin(const float* __restrict__ agg3v,
                                             const float* __restrict__ Win,
                                             const float* __restrict__ bin,
                                             __half* __restrict__ h, int n) {
    int idx = blockIdx.x * 256 + threadIdx.x;
    int node = idx >> 6, f = idx & 63;
    if (node >= n) return;
    float v = bin[f];
    v += agg3v[node * 3 + 0] * Win[0 * 64 + f];
    v += agg3v[node * 3 + 1] * Win[1 * 64 + f];
    v += agg3v[node * 3 + 2] * Win[2 * 64 + f];
    h[(size_t)node * 64 + f] = __float2half(fmaxf(v, 0.f));
}

// dense 64x64 matmul (h fp16 in) + src-side dinv scale, fp16 out
__global__ __launch_bounds__(256) void k_matmul64(const __half* __restrict__ h,
                                                  const float* __restrict__ W,
                                                  const float* __restrict__ dinv,
                                                  __half* __restrict__ t16, int n) {
    __shared__ float Wl[64 * 64];
    __shared__ float Hl[16][68];
    int tid = threadIdx.x;
    for (int i = tid * 4; i < 4096; i += 1024)
        *(float4*)&Wl[i] = *(const float4*)&W[i];
    int nodeBase = blockIdx.x * 16;
    {
        int idx = tid * 4;            // 1024 halves = 16 nodes x 64
        int nl = idx >> 6, k = idx & 63;
        int node = nodeBase + nl;
        float4 v = make_float4(0.f, 0.f, 0.f, 0.f);
        if (node < n) {
            float2 raw = *(const float2*)&h[(size_t)node * 64 + k];  // 4 halves
            const __half2* hp = (const __half2*)&raw;
            float2 p0 = __half22float2(hp[0]);
            float2 p1 = __half22float2(hp[1]);
            v = make_float4(p0.x, p0.y, p1.x, p1.y);
        }
        *(float4*)&Hl[nl][k] = v;
    }
    __syncthreads();
    int nl = tid >> 4;
    int fq = (tid & 15) * 4;
    float4 acc = make_float4(0.f, 0.f, 0.f, 0.f);
#pragma unroll
    for (int k = 0; k < 64; ++k) {
        float hv = Hl[nl][k];
        float4 wv = *(const float4*)&Wl[k * 64 + fq];
        acc.x += hv * wv.x;
        acc.y += hv * wv.y;
        acc.z += hv * wv.z;
        acc.w += hv * wv.w;
    }
    int node = nodeBase + nl;
    if (node < n) {
        float dv = dinv[node];
        __half2* dst = (__half2*)&t16[(size_t)node * 64 + fq];
        dst[0] = __floats2half2_rn(acc.x * dv, acc.y * dv);
        dst[1] = __floats2half2_rn(acc.z * dv, acc.w * dv);
    }
}

// pull aggregation: 1 node/wave; 64 lanes = 8 edge-slots x 8 feat-lanes;
// 16B loads; unroll-2 -> 2 independent gathers in flight per lane.
__global__ __launch_bounds__(256) void k_agg64(const __half* __restrict__ t16,
                                               const int* __restrict__ rowptr,
                                               const int* __restrict__ col,
                                               const float* __restrict__ dinv,
                                               const float* __restrict__ bias,
                                               __half* __restrict__ hout, int n) {
    int node = blockIdx.x * 4 + ((int)threadIdx.x >> 6);
    if (node >= n) return;
    int lane = threadIdx.x & 63;
    int slot = lane >> 3;   // 0..7 edge slot
    int fl   = lane & 7;    // feature lane: feats [fl*8, fl*8+8)
    int beg = rowptr[node], end = rowptr[node + 1];
    float a0 = 0.f, a1 = 0.f, a2 = 0.f, a3 = 0.f, a4 = 0.f, a5 = 0.f, a6 = 0.f, a7 = 0.f;
    int j = beg + slot;
    for (; j + 8 < end; j += 16) {
        int s0 = col[j];
        int s1 = col[j + 8];
        float4 r0 = *(const float4*)(t16 + (size_t)s0 * 64 + fl * 8);
        float4 r1 = *(const float4*)(t16 + (size_t)s1 * 64 + fl * 8);
        const __half2* h0 = (const __half2*)&r0;
        const __half2* h1 = (const __half2*)&r1;
        float2 p;
        p = __half22float2(h0[0]); a0 += p.x; a1 += p.y;
        p = __half22float2(h0[1]); a2 += p.x; a3 += p.y;
        p = __half22float2(h0[2]); a4 += p.x; a5 += p.y;
        p = __half22float2(h0[3]); a6 += p.x; a7 += p.y;
        p = __half22float2(h1[0]); a0 += p.x; a1 += p.y;
        p = __half22float2(h1[1]); a2 += p.x; a3 += p.y;
        p = __half22float2(h1[2]); a4 += p.x; a5 += p.y;
        p = __half22float2(h1[3]); a6 += p.x; a7 += p.y;
    }
    if (j < end) {
        int s0 = col[j];
        float4 r0 = *(const float4*)(t16 + (size_t)s0 * 64 + fl * 8);
        const __half2* h0 = (const __half2*)&r0;
        float2 p;
        p = __half22float2(h0[0]); a0 += p.x; a1 += p.y;
        p = __half22float2(h0[1]); a2 += p.x; a3 += p.y;
        p = __half22float2(h0[2]); a4 += p.x; a5 += p.y;
        p = __half22float2(h0[3]); a6 += p.x; a7 += p.y;
    }
#pragma unroll
    for (int m = 8; m < 64; m <<= 1) {
        a0 += __shfl_xor(a0, m, 64);
        a1 += __shfl_xor(a1, m, 64);
        a2 += __shfl_xor(a2, m, 64);
        a3 += __shfl_xor(a3, m, 64);
        a4 += __shfl_xor(a4, m, 64);
        a5 += __shfl_xor(a5, m, 64);
        a6 += __shfl_xor(a6, m, 64);
        a7 += __shfl_xor(a7, m, 64);
    }
    if (slot == 0) {
        float dv = dinv[node];
        int fo = fl * 8;
        __half2 w0 = __floats2half2_rn(fmaxf(dv * a0 + bias[fo + 0], 0.f),
                                       fmaxf(dv * a1 + bias[fo + 1], 0.f));
        __half2 w1 = __floats2half2_rn(fmaxf(dv * a2 + bias[fo + 2], 0.f),
                                       fmaxf(dv * a3 + bias[fo + 3], 0.f));
        __half2 w2 = __floats2half2_rn(fmaxf(dv * a4 + bias[fo + 4], 0.f),
                                       fmaxf(dv * a5 + bias[fo + 5], 0.f));
        __half2 w3 = __floats2half2_rn(fmaxf(dv * a6 + bias[fo + 6], 0.f),
                                       fmaxf(dv * a7 + bias[fo + 7], 0.f));
        __half2* dst = (__half2*)&hout[(size_t)node * 64 + fo];
        dst[0] = w0; dst[1] = w1; dst[2] = w2; dst[3] = w3;
    }
}

// output transform: t6p[node][0..7] fp16 = dinv * (h @ Wout) padded to 8
__global__ __launch_bounds__(256) void k_tout(const __half* __restrict__ h,
                                              const float* __restrict__ Wout,
                                              const float* __restrict__ dinv,
                                              __half* __restrict__ t6p, int n) {
    __shared__ float Wl6[64 * 6];
    for (int i = threadIdx.x; i < 384; i += 256) Wl6[i] = Wout[i];
    __syncthreads();
    int node = blockIdx.x * 256 + threadIdx.x;
    if (node >= n) return;
    float acc[6] = {0.f, 0.f, 0.f, 0.f, 0.f, 0.f};
#pragma unroll
    for (int k4 = 0; k4 < 16; ++k4) {
        float2 raw = *(const float2*)&h[(size_t)node * 64 + k4 * 4];  // 4 halves
        const __half2* hp = (const __half2*)&raw;
        float2 p0 = __half22float2(hp[0]);
        float2 p1 = __half22float2(hp[1]);
        float hq[4] = {p0.x, p0.y, p1.x, p1.y};
#pragma unroll
        for (int q = 0; q < 4; ++q) {
            int k = k4 * 4 + q;
#pragma unroll
            for (int f = 0; f < 6; ++f) acc[f] += hq[q] * Wl6[k * 6 + f];
        }
    }
    float dv = dinv[node];
    __half2 o0 = __floats2half2_rn(dv * acc[0], dv * acc[1]);
    __half2 o1 = __floats2half2_rn(dv * acc[2], dv * acc[3]);
    __half2 o2 = __floats2half2_rn(dv * acc[4], dv * acc[5]);
    __half2 o3 = __floats2half2_rn(0.f, 0.f);
    __half2* dst = (__half2*)&t6p[(size_t)node * 8];
    dst[0] = o0; dst[1] = o1; dst[2] = o2; dst[3] = o3;
}

// 6-wide aggregation over fp16 padded rows (1.6MB footprint, L2-resident)
__global__ __launch_bounds__(256) void k_agg6(const __half* __restrict__ t6p,
                                              const int* __restrict__ rowptr,
                                              const int* __restrict__ col,
                                              const float* __restrict__ dinv,
                                              const float* __restrict__ bout,
                                              float* __restrict__ out, int n) {
    int i = blockIdx.x * 256 + threadIdx.x;
    if (i >= n) return;
    float a0 = 0.f, a1 = 0.f, a2 = 0.f, a3 = 0.f, a4 = 0.f, a5 = 0.f;
    int beg = rowptr[i], end = rowptr[i + 1];
    int j = beg;
    for (; j + 1 < end; j += 2) {
        int s0 = col[j], s1 = col[j + 1];
        float4 r0 = *(const float4*)(t6p + (size_t)s0 * 8);
        float4 r1 = *(const float4*)(t6p + (size_t)s1 * 8);
        const __half2* h0 = (const __half2*)&r0;
        const __half2* h1 = (const __half2*)&r1;
        float2 p;
        p = __half22float2(h0[0]); a0 += p.x; a1 += p.y;
        p = __half22float2(h0[1]); a2 += p.x; a3 += p.y;
        p = __half22float2(h0[2]); a4 += p.x; a5 += p.y;
        p = __half22float2(h1[0]); a0 += p.x; a1 += p.y;
        p = __half22float2(h1[1]); a2 += p.x; a3 += p.y;
        p = __half22float2(h1[2]); a4 += p.x; a5 += p.y;
    }
    if (j < end) {
        int s0 = col[j];
        float4 r0 = *(const float4*)(t6p + (size_t)s0 * 8);
        const __half2* h0 = (const __half2*)&r0;
        float2 p;
        p = __half22float2(h0[0]); a0 += p.x; a1 += p.y;
        p = __half22float2(h0[1]); a2 += p.x; a3 += p.y;
        p = __half22float2(h0[2]); a4 += p.x; a5 += p.y;
    }
    float dv = dinv[i];
    out[i * 6 + 0] = 1.0f / (1.0f + expf(-(dv * a0 + bout[0])));
    out[i * 6 + 1] = 1.0f / (1.0f + expf(-(dv * a1 + bout[1])));
    out[i * 6 + 2] = 1.0f / (1.0f + expf(-(dv * a2 + bout[2])));
    out[i * 6 + 3] = 1.0f / (1.0f + expf(-(dv * a3 + bout[3])));
    out[i * 6 + 4] = 1.0f / (1.0f + expf(-(dv * a4 + bout[4])));
    out[i * 6 + 5] = 1.0f / (1.0f + expf(-(dv * a5 + bout[5])));
}

// ---------------- host launcher ----------------

extern "C" void kernel_launch(void* const* d_in, const int* in_sizes, int n_in,
                              void* d_out, int out_size, void* d_ws, size_t ws_size,
                              hipStream_t stream) {
    const float* x    = (const float*)d_in[0];
    const int*   eidx = (const int*)d_in[1];
    const float* Win  = (const float*)d_in[2];
    const float* bin  = (const float*)d_in[3];
    const float* Whid = (const float*)d_in[4];
    const float* bhid = (const float*)d_in[5];
    const float* Wout = (const float*)d_in[6];
    const float* bout = (const float*)d_in[7];
    float* out = (float*)d_out;

    const int N = in_sizes[0] / 3;
    const int E = in_sizes[1] / 2;
    const int* srcA = eidx;
    const int* dstA = eidx + E;
    const int TOT = E + N;
    const int NRANGE = (N + RSIZE - 1) / RSIZE;

    char* p = (char*)d_ws;
    auto alloc = [&](size_t bytes) -> void* {
        void* r = (void*)p;
        p += (bytes + 255) & ~(size_t)255;
        return r;
    };
    int*    deg     = (int*)alloc((size_t)N * 4);
    float*  dinv    = (float*)alloc((size_t)N * 4);
    int*    rowptr  = (int*)alloc((size_t)(N + 1) * 4);
    int*    cursor  = (int*)alloc((size_t)N * 4);
    int*    partial = (int*)alloc((size_t)N * 4);
    int*    bsums   = (int*)alloc((size_t)512 * 4);
    int*    col     = (int*)alloc((size_t)TOT * 4);
    float*  xs      = (float*)alloc((size_t)N * 3 * 4);
    float*  agg3buf = (float*)alloc((size_t)N * 3 * 4);
    __half* hbuf    = (__half*)alloc((size_t)N * 64 * 2);  // h (fp16)
    __half* t16     = (__half*)alloc((size_t)N * 64 * 2);  // scaled transform (fp16)
    __half* t6p     = (__half*)alloc((size_t)N * 8 * 2);   // padded 6-wide (fp16)

    const int NB_N = (N + 255) / 256;
    const int NB_E = (E + 255) / 256;
    const int NB_T = (TOT + 255) / 256;

    // CSR build
    k_deg_init<<<NB_N, 256, 0, stream>>>(deg, N);
    k_histp_all<<<NRANGE * NB_E, 256, 0, stream>>>(dstA, deg, E, N, NB_E);
    k_dinv<<<NB_N, 256, 0, stream>>>(deg, dinv, N);
    k_scan1<<<NB_N, SCAN_BS, 0, stream>>>(deg, partial, bsums, N);
    k_scan2<<<1, 512, 0, stream>>>(bsums, NB_N);
    k_scan3<<<NB_N, 256, 0, stream>>>(partial, bsums, deg, rowptr, cursor, N);
    k_fillp_all<<<NRANGE * NB_T, 256, 0, stream>>>(srcA, dstA, cursor, col, E, N, NB_T);

    // input layer
    k_xscale<<<NB_N, 256, 0, stream>>>(x, dinv, xs, N);
    k_agg3<<<NB_N, 256, 0, stream>>>(xs, rowptr, col, dinv, agg3buf, N);
    k_tin<<<(N * 64 + 255) / 256, 256, 0, stream>>>(agg3buf, Win, bin, hbuf, N);

    // hidden layers
    for (int i = 0; i < 6; ++i) {
        k_matmul64<<<(N + 15) / 16, 256, 0, stream>>>(hbuf, Whid + (size_t)i * 4096, dinv, t16, N);
        k_agg64<<<(N + 3) / 4, 256, 0, stream>>>(t16, rowptr, col, dinv, bhid + (size_t)i * 64, hbuf, N);
    }

    // output layer
    k_tout<<<NB_N, 256, 0, stream>>>(hbuf, Wout, dinv, t6p, N);
    k_agg6<<<NB_N, 256, 0, stream>>>(t6p, rowptr, col, dinv, bout, out, N);
}

// Round 9
// 726.107 us; speedup vs baseline: 3.7555x; 1.2791x over previous
//
#include <hip/hip_runtime.h>
#include <hip/hip_fp16.h>
#include <math.h>

#define MAXBKT 512   // buckets of 256 dst nodes; N=100K -> 391 buckets

// ---------------- CSR build (3-phase bucket sort, block-exclusive writes) ----

// phase 1: bucket histogram with LDS pre-aggregation
__global__ __launch_bounds__(256) void k_bcount(const int* __restrict__ dstA,
                                                int E, int N, int nbkt, int* bucketCnt) {
    __shared__ int cnt[MAXBKT];
    for (int i = threadIdx.x; i < nbkt; i += 256) cnt[i] = 0;
    __syncthreads();
    int total = E + N;
    for (int i = blockIdx.x * 256 + threadIdx.x; i < total; i += gridDim.x * 256) {
        int d = (i < E) ? dstA[i] : (i - E);
        atomicAdd(&cnt[d >> 8], 1);
    }
    __syncthreads();
    for (int i = threadIdx.x; i < nbkt; i += 256)
        if (cnt[i]) atomicAdd(&bucketCnt[i], cnt[i]);
}

// phase 2: exclusive scan of bucket sizes (one block)
__global__ __launch_bounds__(MAXBKT) void k_bscan(const int* __restrict__ bucketCnt,
                                                  int* bucketOff, int* bucketCur,
                                                  int nbkt, int total) {
    __shared__ int sm[MAXBKT];
    int tid = threadIdx.x;
    int v = (tid < nbkt) ? bucketCnt[tid] : 0;
    sm[tid] = v;
    __syncthreads();
    for (int off = 1; off < MAXBKT; off <<= 1) {
        int t = 0;
        if (tid >= off) t = sm[tid - off];
        __syncthreads();
        sm[tid] += t;
        __syncthreads();
    }
    if (tid < nbkt) {
        int excl = sm[tid] - v;
        bucketOff[tid] = excl;
        bucketCur[tid] = excl;
    }
    if (tid == 0) bucketOff[nbkt] = total;
}

// phase 3: scatter edges grouped by bucket. Each block reserves a contiguous
// run per bucket (atomicAdd once per bucket per block) -> run writes are
// block-exclusive => single-XCD L2 lines => writes merge (R7 lesson: lines
// written from multiple XCDs never merge; 14x write amplification).
__global__ __launch_bounds__(256) void k_bscat2(const int* __restrict__ srcA,
                                                const int* __restrict__ dstA,
                                                int* bucketCur, unsigned int* bedges,
                                                int E, int N, int nbkt, int chunk) {
    __shared__ int cnt[MAXBKT];
    __shared__ int base[MAXBKT];
    int total = E + N;
    int lo = blockIdx.x * chunk;
    int hi = lo + chunk; if (hi > total) hi = total;
    for (int i = threadIdx.x; i < nbkt; i += 256) cnt[i] = 0;
    __syncthreads();
    for (int i = lo + threadIdx.x; i < hi; i += 256) {
        int d = (i < E) ? dstA[i] : (i - E);
        atomicAdd(&cnt[d >> 8], 1);
    }
    __syncthreads();
    for (int i = threadIdx.x; i < nbkt; i += 256) {
        base[i] = cnt[i] ? atomicAdd(&bucketCur[i], cnt[i]) : 0;
        cnt[i] = 0;
    }
    __syncthreads();
    for (int i = lo + threadIdx.x; i < hi; i += 256) {
        int s, d;
        if (i < E) { s = srcA[i]; d = dstA[i]; }
        else       { s = d = i - E; }
        int b = d >> 8;
        int pos = base[b] + atomicAdd(&cnt[b], 1);
        bedges[pos] = ((unsigned int)(d & 255) << 24) | (unsigned int)s;
    }
}

// phase 4: one block per bucket. LDS degree count (self-loops included in
// bedges) -> LDS scan -> rowptr + dinv; then place col into the bucket's
// dense region (single block = single XCD => full write merge).
__global__ __launch_bounds__(256) void k_bfill2(const unsigned int* __restrict__ bedges,
                                                const int* __restrict__ bucketOff,
                                                int* __restrict__ rowptr,
                                                float* __restrict__ dinv,
                                                int* __restrict__ col,
                                                int N, int total) {
    __shared__ int ldeg[256];
    __shared__ int lcur[256];
    int b = blockIdx.x;
    int tid = threadIdx.x;
    int bo = bucketOff[b], be = bucketOff[b + 1];
    ldeg[tid] = 0;
    __syncthreads();
    for (int j = bo + tid; j < be; j += 256)
        atomicAdd(&ldeg[bedges[j] >> 24], 1);
    __syncthreads();
    int dg = ldeg[tid];
    lcur[tid] = dg;
    __syncthreads();
    for (int off = 1; off < 256; off <<= 1) {
        int t = 0;
        if (tid >= off) t = lcur[tid - off];
        __syncthreads();
        lcur[tid] += t;
        __syncthreads();
    }
    int excl = lcur[tid] - dg;
    int node = (b << 8) + tid;
    if (node < N) {
        rowptr[node] = bo + excl;
        dinv[node] = dg > 0 ? rsqrtf((float)dg) : 0.0f;
    }
    if (b == 0 && tid == 0) rowptr[N] = total;
    __syncthreads();
    lcur[tid] = bo + excl;   // cursor
    __syncthreads();
    for (int j = bo + tid; j < be; j += 256) {
        unsigned int e = bedges[j];
        int pos = atomicAdd(&lcur[e >> 24], 1);
        col[pos] = (int)(e & 0x00FFFFFFu);
    }
}

// ---------------- layer kernels ----------------

__global__ __launch_bounds__(256) void k_xscale(const float* __restrict__ x,
                                                const float* __restrict__ dinv,
                                                float* __restrict__ xs, int n) {
    int i = blockIdx.x * 256 + threadIdx.x;
    if (i >= n) return;
    float dv = dinv[i];
    xs[i * 3 + 0] = dv * x[i * 3 + 0];
    xs[i * 3 + 1] = dv * x[i * 3 + 1];
    xs[i * 3 + 2] = dv * x[i * 3 + 2];
}

__global__ __launch_bounds__(256) void k_agg3(const float* __restrict__ xs,
                                              const int* __restrict__ rowptr,
                                              const int* __restrict__ col,
                                              const float* __restrict__ dinv,
                                              float* __restrict__ out3, int n) {
    int i = blockIdx.x * 256 + threadIdx.x;
    if (i >= n) return;
    float a0 = 0.f, a1 = 0.f, a2 = 0.f;
    int beg = rowptr[i], end = rowptr[i + 1];
    for (int j = beg; j < end; ++j) {
        int s = col[j];
        a0 += xs[s * 3 + 0];
        a1 += xs[s * 3 + 1];
        a2 += xs[s * 3 + 2];
    }
    float dv = dinv[i];
    out3[i * 3 + 0] = dv * a0;
    out3[i * 3 + 1] = dv * a1;
    out3[i * 3 + 2] = dv * a2;
}

// input transform -> h fp16
__global__ __launch_bounds__(256) void k_tin(const float* __restrict__ agg3v,
                                             const float* __restrict__ Win,
                                             const float* __restrict__ bin,
                                             __half* __restrict__ h, int n) {
    int idx = blockIdx.x * 256 + threadIdx.x;
    int node = idx >> 6, f = idx & 63;
    if (node >= n) return;
    float v = bin[f];
    v += agg3v[node * 3 + 0] * Win[0 * 64 + f];
    v += agg3v[node * 3 + 1] * Win[1 * 64 + f];
    v += agg3v[node * 3 + 2] * Win[2 * 64 + f];
    h[(size_t)node * 64 + f] = __float2half(fmaxf(v, 0.f));
}

// dense 64x64 matmul (h fp16 in) + src-side dinv scale, fp16 out
__global__ __launch_bounds__(256) void k_matmul64(const __half* __restrict__ h,
                                                  const float* __restrict__ W,
                                                  const float* __restrict__ dinv,
                                                  __half* __restrict__ t16, int n) {
    __shared__ float Wl[64 * 64];
    __shared__ float Hl[16][68];
    int tid = threadIdx.x;
    for (int i = tid * 4; i < 4096; i += 1024)
        *(float4*)&Wl[i] = *(const float4*)&W[i];
    int nodeBase = blockIdx.x * 16;
    {
        int idx = tid * 4;            // 1024 halves = 16 nodes x 64
        int nl = idx >> 6, k = idx & 63;
        int node = nodeBase + nl;
        float4 v = make_float4(0.f, 0.f, 0.f, 0.f);
        if (node < n) {
            float2 raw = *(const float2*)&h[(size_t)node * 64 + k];  // 4 halves
            const __half2* hp = (const __half2*)&raw;
            float2 p0 = __half22float2(hp[0]);
            float2 p1 = __half22float2(hp[1]);
            v = make_float4(p0.x, p0.y, p1.x, p1.y);
        }
        *(float4*)&Hl[nl][k] = v;
    }
    __syncthreads();
    int nl = tid >> 4;
    int fq = (tid & 15) * 4;
    float4 acc = make_float4(0.f, 0.f, 0.f, 0.f);
#pragma unroll
    for (int k = 0; k < 64; ++k) {
        float hv = Hl[nl][k];
        float4 wv = *(const float4*)&Wl[k * 64 + fq];
        acc.x += hv * wv.x;
        acc.y += hv * wv.y;
        acc.z += hv * wv.z;
        acc.w += hv * wv.w;
    }
    int node = nodeBase + nl;
    if (node < n) {
        float dv = dinv[node];
        __half2* dst = (__half2*)&t16[(size_t)node * 64 + fq];
        dst[0] = __floats2half2_rn(acc.x * dv, acc.y * dv);
        dst[1] = __floats2half2_rn(acc.z * dv, acc.w * dv);
    }
}

// pull aggregation: 1 node/wave; 64 lanes = 8 edge-slots x 8 feat-lanes;
// 16B loads; unroll-2 -> 2 independent gathers in flight per lane.
__global__ __launch_bounds__(256) void k_agg64(const __half* __restrict__ t16,
                                               const int* __restrict__ rowptr,
                                               const int* __restrict__ col,
                                               const float* __restrict__ dinv,
                                               const float* __restrict__ bias,
                                               __half* __restrict__ hout, int n) {
    int node = blockIdx.x * 4 + ((int)threadIdx.x >> 6);
    if (node >= n) return;
    int lane = threadIdx.x & 63;
    int slot = lane >> 3;   // 0..7 edge slot
    int fl   = lane & 7;    // feature lane: feats [fl*8, fl*8+8)
    int beg = rowptr[node], end = rowptr[node + 1];
    float a0 = 0.f, a1 = 0.f, a2 = 0.f, a3 = 0.f, a4 = 0.f, a5 = 0.f, a6 = 0.f, a7 = 0.f;
    int j = beg + slot;
    for (; j + 8 < end; j += 16) {
        int s0 = col[j];
        int s1 = col[j + 8];
        float4 r0 = *(const float4*)(t16 + (size_t)s0 * 64 + fl * 8);
        float4 r1 = *(const float4*)(t16 + (size_t)s1 * 64 + fl * 8);
        const __half2* h0 = (const __half2*)&r0;
        const __half2* h1 = (const __half2*)&r1;
        float2 p;
        p = __half22float2(h0[0]); a0 += p.x; a1 += p.y;
        p = __half22float2(h0[1]); a2 += p.x; a3 += p.y;
        p = __half22float2(h0[2]); a4 += p.x; a5 += p.y;
        p = __half22float2(h0[3]); a6 += p.x; a7 += p.y;
        p = __half22float2(h1[0]); a0 += p.x; a1 += p.y;
        p = __half22float2(h1[1]); a2 += p.x; a3 += p.y;
        p = __half22float2(h1[2]); a4 += p.x; a5 += p.y;
        p = __half22float2(h1[3]); a6 += p.x; a7 += p.y;
    }
    if (j < end) {
        int s0 = col[j];
        float4 r0 = *(const float4*)(t16 + (size_t)s0 * 64 + fl * 8);
        const __half2* h0 = (const __half2*)&r0;
        float2 p;
        p = __half22float2(h0[0]); a0 += p.x; a1 += p.y;
        p = __half22float2(h0[1]); a2 += p.x; a3 += p.y;
        p = __half22float2(h0[2]); a4 += p.x; a5 += p.y;
        p = __half22float2(h0[3]); a6 += p.x; a7 += p.y;
    }
#pragma unroll
    for (int m = 8; m < 64; m <<= 1) {
        a0 += __shfl_xor(a0, m, 64);
        a1 += __shfl_xor(a1, m, 64);
        a2 += __shfl_xor(a2, m, 64);
        a3 += __shfl_xor(a3, m, 64);
        a4 += __shfl_xor(a4, m, 64);
        a5 += __shfl_xor(a5, m, 64);
        a6 += __shfl_xor(a6, m, 64);
        a7 += __shfl_xor(a7, m, 64);
    }
    if (slot == 0) {
        float dv = dinv[node];
        int fo = fl * 8;
        __half2 w0 = __floats2half2_rn(fmaxf(dv * a0 + bias[fo + 0], 0.f),
                                       fmaxf(dv * a1 + bias[fo + 1], 0.f));
        __half2 w1 = __floats2half2_rn(fmaxf(dv * a2 + bias[fo + 2], 0.f),
                                       fmaxf(dv * a3 + bias[fo + 3], 0.f));
        __half2 w2 = __floats2half2_rn(fmaxf(dv * a4 + bias[fo + 4], 0.f),
                                       fmaxf(dv * a5 + bias[fo + 5], 0.f));
        __half2 w3 = __floats2half2_rn(fmaxf(dv * a6 + bias[fo + 6], 0.f),
                                       fmaxf(dv * a7 + bias[fo + 7], 0.f));
        __half2* dst = (__half2*)&hout[(size_t)node * 64 + fo];
        dst[0] = w0; dst[1] = w1; dst[2] = w2; dst[3] = w3;
    }
}

// output transform: t6p[node][0..7] fp16 = dinv * (h @ Wout) padded to 8
__global__ __launch_bounds__(256) void k_tout(const __half* __restrict__ h,
                                              const float* __restrict__ Wout,
                                              const float* __restrict__ dinv,
                                              __half* __restrict__ t6p, int n) {
    __shared__ float Wl6[64 * 6];
    for (int i = threadIdx.x; i < 384; i += 256) Wl6[i] = Wout[i];
    __syncthreads();
    int node = blockIdx.x * 256 + threadIdx.x;
    if (node >= n) return;
    float acc[6] = {0.f, 0.f, 0.f, 0.f, 0.f, 0.f};
#pragma unroll
    for (int k4 = 0; k4 < 16; ++k4) {
        float2 raw = *(const float2*)&h[(size_t)node * 64 + k4 * 4];  // 4 halves
        const __half2* hp = (const __half2*)&raw;
        float2 p0 = __half22float2(hp[0]);
        float2 p1 = __half22float2(hp[1]);
        float hq[4] = {p0.x, p0.y, p1.x, p1.y};
#pragma unroll
        for (int q = 0; q < 4; ++q) {
            int k = k4 * 4 + q;
#pragma unroll
            for (int f = 0; f < 6; ++f) acc[f] += hq[q] * Wl6[k * 6 + f];
        }
    }
    float dv = dinv[node];
    __half2 o0 = __floats2half2_rn(dv * acc[0], dv * acc[1]);
    __half2 o1 = __floats2half2_rn(dv * acc[2], dv * acc[3]);
    __half2 o2 = __floats2half2_rn(dv * acc[4], dv * acc[5]);
    __half2 o3 = __floats2half2_rn(0.f, 0.f);
    __half2* dst = (__half2*)&t6p[(size_t)node * 8];
    dst[0] = o0; dst[1] = o1; dst[2] = o2; dst[3] = o3;
}

// 6-wide aggregation over fp16 padded rows (1.6MB footprint, L2-resident)
__global__ __launch_bounds__(256) void k_agg6(const __half* __restrict__ t6p,
                                              const int* __restrict__ rowptr,
                                              const int* __restrict__ col,
                                              const float* __restrict__ dinv,
                                              const float* __restrict__ bout,
                                              float* __restrict__ out, int n) {
    int i = blockIdx.x * 256 + threadIdx.x;
    if (i >= n) return;
    float a0 = 0.f, a1 = 0.f, a2 = 0.f, a3 = 0.f, a4 = 0.f, a5 = 0.f;
    int beg = rowptr[i], end = rowptr[i + 1];
    int j = beg;
    for (; j + 1 < end; j += 2) {
        int s0 = col[j], s1 = col[j + 1];
        float4 r0 = *(const float4*)(t6p + (size_t)s0 * 8);
        float4 r1 = *(const float4*)(t6p + (size_t)s1 * 8);
        const __half2* h0 = (const __half2*)&r0;
        const __half2* h1 = (const __half2*)&r1;
        float2 p;
        p = __half22float2(h0[0]); a0 += p.x; a1 += p.y;
        p = __half22float2(h0[1]); a2 += p.x; a3 += p.y;
        p = __half22float2(h0[2]); a4 += p.x; a5 += p.y;
        p = __half22float2(h1[0]); a0 += p.x; a1 += p.y;
        p = __half22float2(h1[1]); a2 += p.x; a3 += p.y;
        p = __half22float2(h1[2]); a4 += p.x; a5 += p.y;
    }
    if (j < end) {
        int s0 = col[j];
        float4 r0 = *(const float4*)(t6p + (size_t)s0 * 8);
        const __half2* h0 = (const __half2*)&r0;
        float2 p;
        p = __half22float2(h0[0]); a0 += p.x; a1 += p.y;
        p = __half22float2(h0[1]); a2 += p.x; a3 += p.y;
        p = __half22float2(h0[2]); a4 += p.x; a5 += p.y;
    }
    float dv = dinv[i];
    out[i * 6 + 0] = 1.0f / (1.0f + expf(-(dv * a0 + bout[0])));
    out[i * 6 + 1] = 1.0f / (1.0f + expf(-(dv * a1 + bout[1])));
    out[i * 6 + 2] = 1.0f / (1.0f + expf(-(dv * a2 + bout[2])));
    out[i * 6 + 3] = 1.0f / (1.0f + expf(-(dv * a3 + bout[3])));
    out[i * 6 + 4] = 1.0f / (1.0f + expf(-(dv * a4 + bout[4])));
    out[i * 6 + 5] = 1.0f / (1.0f + expf(-(dv * a5 + bout[5])));
}

// ---------------- host launcher ----------------

extern "C" void kernel_launch(void* const* d_in, const int* in_sizes, int n_in,
                              void* d_out, int out_size, void* d_ws, size_t ws_size,
                              hipStream_t stream) {
    const float* x    = (const float*)d_in[0];
    const int*   eidx = (const int*)d_in[1];
    const float* Win  = (const float*)d_in[2];
    const float* bin  = (const float*)d_in[3];
    const float* Whid = (const float*)d_in[4];
    const float* bhid = (const float*)d_in[5];
    const float* Wout = (const float*)d_in[6];
    const float* bout = (const float*)d_in[7];
    float* out = (float*)d_out;

    const int N = in_sizes[0] / 3;
    const int E = in_sizes[1] / 2;
    const int* srcA = eidx;
    const int* dstA = eidx + E;
    const int TOT = E + N;
    const int NBKT = (N + 255) >> 8;           // 391 for N=100K (<= MAXBKT)

    char* p = (char*)d_ws;
    auto alloc = [&](size_t bytes) -> void* {
        void* r = (void*)p;
        p += (bytes + 255) & ~(size_t)255;
        return r;
    };
    float*        dinv      = (float*)alloc((size_t)N * 4);
    int*          rowptr    = (int*)alloc((size_t)(N + 1) * 4);
    int*          bucketCnt = (int*)alloc((size_t)MAXBKT * 4);
    int*          bucketOff = (int*)alloc((size_t)(MAXBKT + 1) * 4);
    int*          bucketCur = (int*)alloc((size_t)MAXBKT * 4);
    unsigned int* bedges    = (unsigned int*)alloc((size_t)TOT * 4);
    int*          col       = (int*)alloc((size_t)TOT * 4);
    float*        xs        = (float*)alloc((size_t)N * 3 * 4);
    float*        agg3buf   = (float*)alloc((size_t)N * 3 * 4);
    __half*       hbuf      = (__half*)alloc((size_t)N * 64 * 2);
    __half*       t16       = (__half*)alloc((size_t)N * 64 * 2);
    __half*       t6p       = (__half*)alloc((size_t)N * 8 * 2);

    const int NB_N = (N + 255) / 256;

    // CSR build (4 kernels + 1 memset)
    hipMemsetAsync(bucketCnt, 0, (size_t)MAXBKT * 4, stream);
    k_bcount<<<256, 256, 0, stream>>>(dstA, E, N, NBKT, bucketCnt);
    k_bscan<<<1, MAXBKT, 0, stream>>>(bucketCnt, bucketOff, bucketCur, NBKT, TOT);
    const int CHUNK = (TOT + 255) / 256;
    k_bscat2<<<256, 256, 0, stream>>>(srcA, dstA, bucketCur, bedges, E, N, NBKT, CHUNK);
    k_bfill2<<<NBKT, 256, 0, stream>>>(bedges, bucketOff, rowptr, dinv, col, N, TOT);

    // input layer
    k_xscale<<<NB_N, 256, 0, stream>>>(x, dinv, xs, N);
    k_agg3<<<NB_N, 256, 0, stream>>>(xs, rowptr, col, dinv, agg3buf, N);
    k_tin<<<(N * 64 + 255) / 256, 256, 0, stream>>>(agg3buf, Win, bin, hbuf, N);

    // hidden layers
    for (int i = 0; i < 6; ++i) {
        k_matmul64<<<(N + 15) / 16, 256, 0, stream>>>(hbuf, Whid + (size_t)i * 4096, dinv, t16, N);
        k_agg64<<<(N + 3) / 4, 256, 0, stream>>>(t16, rowptr, col, dinv, bhid + (size_t)i * 64, hbuf, N);
    }

    // output layer
    k_tout<<<NB_N, 256, 0, stream>>>(hbuf, Wout, dinv, t6p, N);
    k_agg6<<<NB_N, 256, 0, stream>>>(t6p, rowptr, col, dinv, bout, out, N);
}

// Round 12
// 683.286 us; speedup vs baseline: 3.9908x; 1.0627x over previous
//
#include <hip/hip_runtime.h>
#include <hip/hip_fp16.h>
#include <math.h>

#define MAXBKT 512   // buckets of 256 dst nodes; N=100K -> 391 buckets

// ---------------- CSR build (bucket sort, block-exclusive writes) ----------

__global__ __launch_bounds__(256) void k_bcount(const int* __restrict__ dstA,
                                                int E, int N, int nbkt, int* bucketCnt) {
    __shared__ int cnt[MAXBKT];
    for (int i = threadIdx.x; i < nbkt; i += 256) cnt[i] = 0;
    __syncthreads();
    int total = E + N;
    for (int i = blockIdx.x * 256 + threadIdx.x; i < total; i += gridDim.x * 256) {
        int d = (i < E) ? dstA[i] : (i - E);
        atomicAdd(&cnt[d >> 8], 1);
    }
    __syncthreads();
    for (int i = threadIdx.x; i < nbkt; i += 256)
        if (cnt[i]) atomicAdd(&bucketCnt[i], cnt[i]);
}

__global__ __launch_bounds__(MAXBKT) void k_bscan(const int* __restrict__ bucketCnt,
                                                  int* bucketOff, int* bucketCur,
                                                  int nbkt, int total) {
    __shared__ int sm[MAXBKT];
    int tid = threadIdx.x;
    int v = (tid < nbkt) ? bucketCnt[tid] : 0;
    sm[tid] = v;
    __syncthreads();
    for (int off = 1; off < MAXBKT; off <<= 1) {
        int t = 0;
        if (tid >= off) t = sm[tid - off];
        __syncthreads();
        sm[tid] += t;
        __syncthreads();
    }
    if (tid < nbkt) {
        int excl = sm[tid] - v;
        bucketOff[tid] = excl;
        bucketCur[tid] = excl;
    }
    if (tid == 0) bucketOff[nbkt] = total;
}

__global__ __launch_bounds__(256) void k_bscat2(const int* __restrict__ srcA,
                                                const int* __restrict__ dstA,
                                                int* bucketCur, unsigned int* bedges,
                                                int E, int N, int nbkt, int chunk) {
    __shared__ int cnt[MAXBKT];
    __shared__ int base[MAXBKT];
    int total = E + N;
    int lo = blockIdx.x * chunk;
    int hi = lo + chunk; if (hi > total) hi = total;
    for (int i = threadIdx.x; i < nbkt; i += 256) cnt[i] = 0;
    __syncthreads();
    for (int i = lo + threadIdx.x; i < hi; i += 256) {
        int d = (i < E) ? dstA[i] : (i - E);
        atomicAdd(&cnt[d >> 8], 1);
    }
    __syncthreads();
    for (int i = threadIdx.x; i < nbkt; i += 256) {
        base[i] = cnt[i] ? atomicAdd(&bucketCur[i], cnt[i]) : 0;
        cnt[i] = 0;
    }
    __syncthreads();
    for (int i = lo + threadIdx.x; i < hi; i += 256) {
        int s, d;
        if (i < E) { s = srcA[i]; d = dstA[i]; }
        else       { s = d = i - E; }
        int b = d >> 8;
        int pos = base[b] + atomicAdd(&cnt[b], 1);
        bedges[pos] = ((unsigned int)(d & 255) << 24) | (unsigned int)s;
    }
}

// one block per bucket: degree count -> scan -> rowptr + dinv + xs (fused
// xscale), then place col into the bucket's dense region.
__global__ __launch_bounds__(256) void k_bfill2(const unsigned int* __restrict__ bedges,
                                                const int* __restrict__ bucketOff,
                                                const float* __restrict__ x,
                                                int* __restrict__ rowptr,
                                                float* __restrict__ dinv,
                                                float* __restrict__ xs,
                                                int* __restrict__ col,
                                                int N, int total) {
    __shared__ int ldeg[256];
    __shared__ int lcur[256];
    int b = blockIdx.x;
    int tid = threadIdx.x;
    int bo = bucketOff[b], be = bucketOff[b + 1];
    ldeg[tid] = 0;
    __syncthreads();
    for (int j = bo + tid; j < be; j += 256)
        atomicAdd(&ldeg[bedges[j] >> 24], 1);
    __syncthreads();
    int dg = ldeg[tid];
    lcur[tid] = dg;
    __syncthreads();
    for (int off = 1; off < 256; off <<= 1) {
        int t = 0;
        if (tid >= off) t = lcur[tid - off];
        __syncthreads();
        lcur[tid] += t;
        __syncthreads();
    }
    int excl = lcur[tid] - dg;
    int node = (b << 8) + tid;
    if (node < N) {
        rowptr[node] = bo + excl;
        float dv = dg > 0 ? rsqrtf((float)dg) : 0.0f;
        dinv[node] = dv;
        xs[node * 3 + 0] = dv * x[node * 3 + 0];
        xs[node * 3 + 1] = dv * x[node * 3 + 1];
        xs[node * 3 + 2] = dv * x[node * 3 + 2];
    }
    if (b == 0 && tid == 0) rowptr[N] = total;
    __syncthreads();
    lcur[tid] = bo + excl;
    __syncthreads();
    for (int j = bo + tid; j < be; j += 256) {
        unsigned int e = bedges[j];
        int pos = atomicAdd(&lcur[e >> 24], 1);
        col[pos] = (int)(e & 0x00FFFFFFu);
    }
}

// ---------------- layer kernels ----------------

__global__ __launch_bounds__(256) void k_agg3(const float* __restrict__ xs,
                                              const int* __restrict__ rowptr,
                                              const int* __restrict__ col,
                                              const float* __restrict__ dinv,
                                              float* __restrict__ out3, int n) {
    int i = blockIdx.x * 256 + threadIdx.x;
    if (i >= n) return;
    float a0 = 0.f, a1 = 0.f, a2 = 0.f;
    int beg = rowptr[i], end = rowptr[i + 1];
    for (int j = beg; j < end; ++j) {
        int s = col[j];
        a0 += xs[s * 3 + 0];
        a1 += xs[s * 3 + 1];
        a2 += xs[s * 3 + 2];
    }
    float dv = dinv[i];
    out3[i * 3 + 0] = dv * a0;
    out3[i * 3 + 1] = dv * a1;
    out3[i * 3 + 2] = dv * a2;
}

// fused: h0 = relu(agg3 @ Win + bin); t1 = fp16(dinv * (h0 @ W0))
__global__ __launch_bounds__(256) void k_tin_mm(const float* __restrict__ agg3v,
                                                const float* __restrict__ Win,
                                                const float* __restrict__ bin,
                                                const float* __restrict__ W0,
                                                const float* __restrict__ dinv,
                                                __half* __restrict__ tout, int n) {
    __shared__ float Wl[64 * 64];
    __shared__ float Hl[16][68];
    int tid = threadIdx.x;
    for (int i = tid * 4; i < 4096; i += 1024)
        *(float4*)&Wl[i] = *(const float4*)&W0[i];
    int nodeBase = blockIdx.x * 16;
    {
        int idx = tid * 4;
        int nl = idx >> 6, f0 = idx & 63;
        int node = nodeBase + nl;
        float a0 = 0.f, a1 = 0.f, a2 = 0.f;
        if (node < n) {
            a0 = agg3v[node * 3 + 0];
            a1 = agg3v[node * 3 + 1];
            a2 = agg3v[node * 3 + 2];
        }
        float4 hv;
        float* hp = (float*)&hv;
#pragma unroll
        for (int q = 0; q < 4; ++q) {
            int f = f0 + q;
            float v = bin[f] + a0 * Win[f] + a1 * Win[64 + f] + a2 * Win[128 + f];
            hp[q] = fmaxf(v, 0.f);
        }
        *(float4*)&Hl[nl][f0] = hv;
    }
    __syncthreads();
    int nl = tid >> 4;
    int fq = (tid & 15) * 4;
    float4 acc = make_float4(0.f, 0.f, 0.f, 0.f);
#pragma unroll
    for (int k = 0; k < 64; ++k) {
        float hv = Hl[nl][k];
        float4 wv = *(const float4*)&Wl[k * 64 + fq];
        acc.x += hv * wv.x;
        acc.y += hv * wv.y;
        acc.z += hv * wv.z;
        acc.w += hv * wv.w;
    }
    int node = nodeBase + nl;
    if (node < n) {
        float dv = dinv[node];
        __half2* dst = (__half2*)&tout[(size_t)node * 64 + fq];
        dst[0] = __floats2half2_rn(acc.x * dv, acc.y * dv);
        dst[1] = __floats2half2_rn(acc.z * dv, acc.w * dv);
    }
}

// fused hidden layer: h = relu(dinv*agg(tin)+bias) [LDS]; tnext = fp16(dinv*(h@W))
// 4 waves/block, each wave gathers 4 nodes (64 lanes = 8 edge-slots x 8 feat-lanes)
__global__ __launch_bounds__(256) void k_aggmm64(const __half* __restrict__ tin,
                                                 const int* __restrict__ rowptr,
                                                 const int* __restrict__ col,
                                                 const float* __restrict__ dinv,
                                                 const float* __restrict__ bias,
                                                 const float* __restrict__ W,
                                                 __half* __restrict__ tnext, int n) {
    __shared__ float Wl[64 * 64];
    __shared__ float Hl[16][68];
    int tid = threadIdx.x;
    for (int i = tid * 4; i < 4096; i += 1024)
        *(float4*)&Wl[i] = *(const float4*)&W[i];
    int nodeBase = blockIdx.x * 16;
    int wv = tid >> 6;
    int lane = tid & 63;
    int slot = lane >> 3;
    int fl = lane & 7;
#pragma unroll
    for (int k4 = 0; k4 < 4; ++k4) {
        int nl = wv * 4 + k4;
        int node = nodeBase + nl;
        float a0 = 0.f, a1 = 0.f, a2 = 0.f, a3 = 0.f, a4 = 0.f, a5 = 0.f, a6 = 0.f, a7 = 0.f;
        if (node < n) {
            int beg = rowptr[node], end = rowptr[node + 1];
            int j = beg + slot;
            for (; j + 8 < end; j += 16) {
                int s0 = col[j];
                int s1 = col[j + 8];
                float4 r0 = *(const float4*)(tin + (size_t)s0 * 64 + fl * 8);
                float4 r1 = *(const float4*)(tin + (size_t)s1 * 64 + fl * 8);
                const __half2* h0 = (const __half2*)&r0;
                const __half2* h1 = (const __half2*)&r1;
                float2 p;
                p = __half22float2(h0[0]); a0 += p.x; a1 += p.y;
                p = __half22float2(h0[1]); a2 += p.x; a3 += p.y;
                p = __half22float2(h0[2]); a4 += p.x; a5 += p.y;
                p = __half22float2(h0[3]); a6 += p.x; a7 += p.y;
                p = __half22float2(h1[0]); a0 += p.x; a1 += p.y;
                p = __half22float2(h1[1]); a2 += p.x; a3 += p.y;
                p = __half22float2(h1[2]); a4 += p.x; a5 += p.y;
                p = __half22float2(h1[3]); a6 += p.x; a7 += p.y;
            }
            if (j < end) {
                int s0 = col[j];
                float4 r0 = *(const float4*)(tin + (size_t)s0 * 64 + fl * 8);
                const __half2* h0 = (const __half2*)&r0;
                float2 p;
                p = __half22float2(h0[0]); a0 += p.x; a1 += p.y;
                p = __half22float2(h0[1]); a2 += p.x; a3 += p.y;
                p = __half22float2(h0[2]); a4 += p.x; a5 += p.y;
                p = __half22float2(h0[3]); a6 += p.x; a7 += p.y;
            }
        }
#pragma unroll
        for (int m = 8; m < 64; m <<= 1) {
            a0 += __shfl_xor(a0, m, 64);
            a1 += __shfl_xor(a1, m, 64);
            a2 += __shfl_xor(a2, m, 64);
            a3 += __shfl_xor(a3, m, 64);
            a4 += __shfl_xor(a4, m, 64);
            a5 += __shfl_xor(a5, m, 64);
            a6 += __shfl_xor(a6, m, 64);
            a7 += __shfl_xor(a7, m, 64);
        }
        if (slot == 0) {
            float dv = (node < n) ? dinv[node] : 0.f;
            int fo = fl * 8;
            float4 w0, w1;
            w0.x = fmaxf(dv * a0 + bias[fo + 0], 0.f);
            w0.y = fmaxf(dv * a1 + bias[fo + 1], 0.f);
            w0.z = fmaxf(dv * a2 + bias[fo + 2], 0.f);
            w0.w = fmaxf(dv * a3 + bias[fo + 3], 0.f);
            w1.x = fmaxf(dv * a4 + bias[fo + 4], 0.f);
            w1.y = fmaxf(dv * a5 + bias[fo + 5], 0.f);
            w1.z = fmaxf(dv * a6 + bias[fo + 6], 0.f);
            w1.w = fmaxf(dv * a7 + bias[fo + 7], 0.f);
            *(float4*)&Hl[nl][fo] = w0;
            *(float4*)&Hl[nl][fo + 4] = w1;
        }
    }
    __syncthreads();
    int nl = tid >> 4;
    int fq = (tid & 15) * 4;
    float4 acc = make_float4(0.f, 0.f, 0.f, 0.f);
#pragma unroll
    for (int k = 0; k < 64; ++k) {
        float hv = Hl[nl][k];
        float4 wv = *(const float4*)&Wl[k * 64 + fq];
        acc.x += hv * wv.x;
        acc.y += hv * wv.y;
        acc.z += hv * wv.z;
        acc.w += hv * wv.w;
    }
    int node = nodeBase + nl;
    if (node < n) {
        float dv = dinv[node];
        __half2* dst = (__half2*)&tnext[(size_t)node * 64 + fq];
        dst[0] = __floats2half2_rn(acc.x * dv, acc.y * dv);
        dst[1] = __floats2half2_rn(acc.z * dv, acc.w * dv);
    }
}

// fused last hidden + output transform: h6 = relu(dinv*agg(t6)+b5) [LDS];
// t6p = fp16(dinv * (h6 @ Wout)) padded to 8
__global__ __launch_bounds__(256) void k_aggtout(const __half* __restrict__ tin,
                                                 const int* __restrict__ rowptr,
                                                 const int* __restrict__ col,
                                                 const float* __restrict__ dinv,
                                                 const float* __restrict__ bias,
                                                 const float* __restrict__ Wout,
                                                 __half* __restrict__ t6p, int n) {
    __shared__ float Wl6[64 * 6];
    __shared__ float Hl[16][68];
    int tid = threadIdx.x;
    for (int i = tid; i < 384; i += 256) Wl6[i] = Wout[i];
    int nodeBase = blockIdx.x * 16;
    int wv = tid >> 6;
    int lane = tid & 63;
    int slot = lane >> 3;
    int fl = lane & 7;
#pragma unroll
    for (int k4 = 0; k4 < 4; ++k4) {
        int nl = wv * 4 + k4;
        int node = nodeBase + nl;
        float a0 = 0.f, a1 = 0.f, a2 = 0.f, a3 = 0.f, a4 = 0.f, a5 = 0.f, a6 = 0.f, a7 = 0.f;
        if (node < n) {
            int beg = rowptr[node], end = rowptr[node + 1];
            int j = beg + slot;
            for (; j + 8 < end; j += 16) {
                int s0 = col[j];
                int s1 = col[j + 8];
                float4 r0 = *(const float4*)(tin + (size_t)s0 * 64 + fl * 8);
                float4 r1 = *(const float4*)(tin + (size_t)s1 * 64 + fl * 8);
                const __half2* h0 = (const __half2*)&r0;
                const __half2* h1 = (const __half2*)&r1;
                float2 p;
                p = __half22float2(h0[0]); a0 += p.x; a1 += p.y;
                p = __half22float2(h0[1]); a2 += p.x; a3 += p.y;
                p = __half22float2(h0[2]); a4 += p.x; a5 += p.y;
                p = __half22float2(h0[3]); a6 += p.x; a7 += p.y;
                p = __half22float2(h1[0]); a0 += p.x; a1 += p.y;
                p = __half22float2(h1[1]); a2 += p.x; a3 += p.y;
                p = __half22float2(h1[2]); a4 += p.x; a5 += p.y;
                p = __half22float2(h1[3]); a6 += p.x; a7 += p.y;
            }
            if (j < end) {
                int s0 = col[j];
                float4 r0 = *(const float4*)(tin + (size_t)s0 * 64 + fl * 8);
                const __half2* h0 = (const __half2*)&r0;
                float2 p;
                p = __half22float2(h0[0]); a0 += p.x; a1 += p.y;
                p = __half22float2(h0[1]); a2 += p.x; a3 += p.y;
                p = __half22float2(h0[2]); a4 += p.x; a5 += p.y;
                p = __half22float2(h0[3]); a6 += p.x; a7 += p.y;
            }
        }
#pragma unroll
        for (int m = 8; m < 64; m <<= 1) {
            a0 += __shfl_xor(a0, m, 64);
            a1 += __shfl_xor(a1, m, 64);
            a2 += __shfl_xor(a2, m, 64);
            a3 += __shfl_xor(a3, m, 64);
            a4 += __shfl_xor(a4, m, 64);
            a5 += __shfl_xor(a5, m, 64);
            a6 += __shfl_xor(a6, m, 64);
            a7 += __shfl_xor(a7, m, 64);
        }
        if (slot == 0) {
            float dv = (node < n) ? dinv[node] : 0.f;
            int fo = fl * 8;
            float4 w0, w1;
            w0.x = fmaxf(dv * a0 + bias[fo + 0], 0.f);
            w0.y = fmaxf(dv * a1 + bias[fo + 1], 0.f);
            w0.z = fmaxf(dv * a2 + bias[fo + 2], 0.f);
            w0.w = fmaxf(dv * a3 + bias[fo + 3], 0.f);
            w1.x = fmaxf(dv * a4 + bias[fo + 4], 0.f);
            w1.y = fmaxf(dv * a5 + bias[fo + 5], 0.f);
            w1.z = fmaxf(dv * a6 + bias[fo + 6], 0.f);
            w1.w = fmaxf(dv * a7 + bias[fo + 7], 0.f);
            *(float4*)&Hl[nl][fo] = w0;
            *(float4*)&Hl[nl][fo + 4] = w1;
        }
    }
    __syncthreads();
    int nl = tid >> 4;
    int f = tid & 15;
    int node = nodeBase + nl;
    if (node < n && f < 8) {
        __half o = __float2half(0.f);
        if (f < 6) {
            float acc = 0.f;
#pragma unroll
            for (int k = 0; k < 64; ++k) acc += Hl[nl][k] * Wl6[k * 6 + f];
            o = __float2half(dinv[node] * acc);
        }
        t6p[(size_t)node * 8 + f] = o;
    }
}

// 6-wide aggregation over fp16 padded rows (1.6MB, L2-resident)
__global__ __launch_bounds__(256) void k_agg6(const __half* __restrict__ t6p,
                                              const int* __restrict__ rowptr,
                                              const int* __restrict__ col,
                                              const float* __restrict__ dinv,
                                              const float* __restrict__ bout,
                                              float* __restrict__ out, int n) {
    int i = blockIdx.x * 256 + threadIdx.x;
    if (i >= n) return;
    float a0 = 0.f, a1 = 0.f, a2 = 0.f, a3 = 0.f, a4 = 0.f, a5 = 0.f;
    int beg = rowptr[i], end = rowptr[i + 1];
    int j = beg;
    for (; j + 1 < end; j += 2) {
        int s0 = col[j], s1 = col[j + 1];
        float4 r0 = *(const float4*)(t6p + (size_t)s0 * 8);
        float4 r1 = *(const float4*)(t6p + (size_t)s1 * 8);
        const __half2* h0 = (const __half2*)&r0;
        const __half2* h1 = (const __half2*)&r1;
        float2 p;
        p = __half22float2(h0[0]); a0 += p.x; a1 += p.y;
        p = __half22float2(h0[1]); a2 += p.x; a3 += p.y;
        p = __half22float2(h0[2]); a4 += p.x; a5 += p.y;
        p = __half22float2(h1[0]); a0 += p.x; a1 += p.y;
        p = __half22float2(h1[1]); a2 += p.x; a3 += p.y;
        p = __half22float2(h1[2]); a4 += p.x; a5 += p.y;
    }
    if (j < end) {
        int s0 = col[j];
        float4 r0 = *(const float4*)(t6p + (size_t)s0 * 8);
        const __half2* h0 = (const __half2*)&r0;
        float2 p;
        p = __half22float2(h0[0]); a0 += p.x; a1 += p.y;
        p = __half22float2(h0[1]); a2 += p.x; a3 += p.y;
        p = __half22float2(h0[2]); a4 += p.x; a5 += p.y;
    }
    float dv = dinv[i];
    out[i * 6 + 0] = 1.0f / (1.0f + expf(-(dv * a0 + bout[0])));
    out[i * 6 + 1] = 1.0f / (1.0f + expf(-(dv * a1 + bout[1])));
    out[i * 6 + 2] = 1.0f / (1.0f + expf(-(dv * a2 + bout[2])));
    out[i * 6 + 3] = 1.0f / (1.0f + expf(-(dv * a3 + bout[3])));
    out[i * 6 + 4] = 1.0f / (1.0f + expf(-(dv * a4 + bout[4])));
    out[i * 6 + 5] = 1.0f / (1.0f + expf(-(dv * a5 + bout[5])));
}

// ---------------- host launcher ----------------

extern "C" void kernel_launch(void* const* d_in, const int* in_sizes, int n_in,
                              void* d_out, int out_size, void* d_ws, size_t ws_size,
                              hipStream_t stream) {
    const float* x    = (const float*)d_in[0];
    const int*   eidx = (const int*)d_in[1];
    const float* Win  = (const float*)d_in[2];
    const float* bin  = (const float*)d_in[3];
    const float* Whid = (const float*)d_in[4];
    const float* bhid = (const float*)d_in[5];
    const float* Wout = (const float*)d_in[6];
    const float* bout = (const float*)d_in[7];
    float* out = (float*)d_out;

    const int N = in_sizes[0] / 3;
    const int E = in_sizes[1] / 2;
    const int* srcA = eidx;
    const int* dstA = eidx + E;
    const int TOT = E + N;
    const int NBKT = (N + 255) >> 8;

    char* p = (char*)d_ws;
    auto alloc = [&](size_t bytes) -> void* {
        void* r = (void*)p;
        p += (bytes + 255) & ~(size_t)255;
        return r;
    };
    float*        dinv      = (float*)alloc((size_t)N * 4);
    int*          rowptr    = (int*)alloc((size_t)(N + 1) * 4);
    int*          bucketCnt = (int*)alloc((size_t)MAXBKT * 4);
    int*          bucketOff = (int*)alloc((size_t)(MAXBKT + 1) * 4);
    int*          bucketCur = (int*)alloc((size_t)MAXBKT * 4);
    unsigned int* bedges    = (unsigned int*)alloc((size_t)TOT * 4);
    int*          col       = (int*)alloc((size_t)TOT * 4);
    float*        xs        = (float*)alloc((size_t)N * 3 * 4);
    float*        agg3buf   = (float*)alloc((size_t)N * 3 * 4);
    __half*       tA        = (__half*)alloc((size_t)N * 64 * 2);
    __half*       tB        = (__half*)alloc((size_t)N * 64 * 2);
    __half*       t6p       = (__half*)alloc((size_t)N * 8 * 2);

    const int NB_N = (N + 255) / 256;
    const int NB16 = (N + 15) / 16;

    // CSR build
    hipMemsetAsync(bucketCnt, 0, (size_t)MAXBKT * 4, stream);
    k_bcount<<<512, 256, 0, stream>>>(dstA, E, N, NBKT, bucketCnt);
    k_bscan<<<1, MAXBKT, 0, stream>>>(bucketCnt, bucketOff, bucketCur, NBKT, TOT);
    const int CHUNK = (TOT + 511) / 512;
    k_bscat2<<<512, 256, 0, stream>>>(srcA, dstA, bucketCur, bedges, E, N, NBKT, CHUNK);
    k_bfill2<<<NBKT, 256, 0, stream>>>(bedges, bucketOff, x, rowptr, dinv, xs, col, N, TOT);

    // input layer: agg3 -> fused tin+matmul(W_hid[0]) -> t1
    k_agg3<<<NB_N, 256, 0, stream>>>(xs, rowptr, col, dinv, agg3buf, N);
    k_tin_mm<<<NB16, 256, 0, stream>>>(agg3buf, Win, bin, Whid, dinv, tA, N);

    // hidden layers 1..5 fused: t_i -> h_i -> t_{i+1}
    __half* tin = tA;
    __half* tnx = tB;
    for (int i = 1; i <= 5; ++i) {
        k_aggmm64<<<NB16, 256, 0, stream>>>(tin, rowptr, col, dinv,
                                            bhid + (size_t)(i - 1) * 64,
                                            Whid + (size_t)i * 4096, tnx, N);
        __half* tmp = tin; tin = tnx; tnx = tmp;
    }

    // last hidden + output transform fused: t6 -> h6 -> t6p
    k_aggtout<<<NB16, 256, 0, stream>>>(tin, rowptr, col, dinv,
                                        bhid + (size_t)5 * 64, Wout, t6p, N);

    // final aggregation + sigmoid
    k_agg6<<<NB_N, 256, 0, stream>>>(t6p, rowptr, col, dinv, bout, out, N);
}